// Round 14
// baseline (193.973 us; speedup 1.0000x reference)
//
#include <hip/hip_runtime.h>
#include <hip/hip_bf16.h>
#include <cmath>

#define NTHREADS 256

constexpr int IN_CHANS = 6;
constexpr int EMBED = 768;
constexpr int DEC_EMBED = 512;

typedef __attribute__((ext_vector_type(8))) short short8;
typedef __attribute__((ext_vector_type(4))) short short4_t;
typedef __attribute__((ext_vector_type(4))) float f32x4;
typedef __attribute__((ext_vector_type(4))) unsigned int uint4_t;

__device__ __forceinline__ void gload_lds16(const short* g, short* l) {
    __builtin_amdgcn_global_load_lds((const __attribute__((address_space(1))) void*)g,
                                     (__attribute__((address_space(3))) void*)l, 16, 0, 0);
}

__device__ __forceinline__ float gelu_f(float x) {
    return 0.5f * x * (1.0f + erff(x * 0.70710678118654752f));
}

// ---- fused: h=gelu(coords@w1+b1) bf16 + counts + copies + w2 transpose ----

__global__ void hc_kernel(const float* __restrict__ coords,
                          const float* __restrict__ w1e, const float* __restrict__ b1e,
                          const float* __restrict__ w1d, const float* __restrict__ b1d,
                          const int* __restrict__ q, const int* __restrict__ seg,
                          const float* __restrict__ sel, const float* __restrict__ selc,
                          const float* __restrict__ w2e, const float* __restrict__ w2d,
                          __hip_bfloat16* __restrict__ hE, __hip_bfloat16* __restrict__ hD,
                          __hip_bfloat16* __restrict__ w2tE, __hip_bfloat16* __restrict__ w2tD,
                          int* __restrict__ qcount, int* __restrict__ segcnt,
                          float* __restrict__ out1, float* __restrict__ out2,
                          int hcBlocks, int num_seg, int npts) {
    __shared__ float tile[32][33];
    if ((int)blockIdx.x >= hcBlocks) {
        int b = blockIdx.x - hcBlocks;
        const float* src; __hip_bfloat16* dst; int n;
        const int ntE = (EMBED / 32) * (EMBED / 32);
        if (b < ntE) { src = w2e; dst = w2tE; n = EMBED; }
        else         { b -= ntE; src = w2d; dst = w2tD; n = DEC_EMBED; }
        int tpr = n / 32;
        int tr = b / tpr, tc = b % tpr;
        int tx = threadIdx.x & 31, ty = threadIdx.x >> 5;
        #pragma unroll
        for (int i = 0; i < 4; ++i)
            tile[ty + 8 * i][tx] = src[(size_t)(tr * 32 + ty + 8 * i) * n + tc * 32 + tx];
        __syncthreads();
        #pragma unroll
        for (int i = 0; i < 4; ++i)
            dst[(size_t)(tc * 32 + ty + 8 * i) * n + tr * 32 + tx] =
                __float2bfloat16(tile[tx][ty + 8 * i]);
        return;
    }
    const unsigned nE8 = (unsigned)num_seg * (EMBED / 8);
    const unsigned nD8 = (unsigned)num_seg * (DEC_EMBED / 8);
    const unsigned t0 = nE8;
    const unsigned t1 = t0 + nD8;
    const unsigned t2 = t1 + (unsigned)npts;                 // counts
    const unsigned n14 = (unsigned)npts * IN_CHANS / 4;      // out1 float4s
    const unsigned t3 = t2 + n14;
    const unsigned n24 = (unsigned)npts * 3 / 4;             // out2 float4s
    const unsigned t4 = t3 + n24;
    const unsigned stride = (unsigned)hcBlocks * blockDim.x;
    for (unsigned idx = blockIdx.x * blockDim.x + threadIdx.x; idx < t4; idx += stride) {
        if (idx < t0) {
            unsigned r = idx / (EMBED / 8), d = (idx % (EMBED / 8)) * 8;
            float c0 = coords[r * 3 + 0], c1 = coords[r * 3 + 1], c2 = coords[r * 3 + 2];
            float4 wa0 = *reinterpret_cast<const float4*>(w1e + 0 * EMBED + d);
            float4 wa1 = *reinterpret_cast<const float4*>(w1e + 0 * EMBED + d + 4);
            float4 wb0 = *reinterpret_cast<const float4*>(w1e + 1 * EMBED + d);
            float4 wb1 = *reinterpret_cast<const float4*>(w1e + 1 * EMBED + d + 4);
            float4 wc0 = *reinterpret_cast<const float4*>(w1e + 2 * EMBED + d);
            float4 wc1 = *reinterpret_cast<const float4*>(w1e + 2 * EMBED + d + 4);
            float4 bb0 = *reinterpret_cast<const float4*>(b1e + d);
            float4 bb1 = *reinterpret_cast<const float4*>(b1e + d + 4);
            union { short8 v; __hip_bfloat16 h[8]; } u;
            #pragma unroll
            for (int i = 0; i < 4; ++i)
                u.h[i] = __float2bfloat16(gelu_f(c0 * (&wa0.x)[i] + c1 * (&wb0.x)[i]
                                               + c2 * (&wc0.x)[i] + (&bb0.x)[i]));
            #pragma unroll
            for (int i = 0; i < 4; ++i)
                u.h[4 + i] = __float2bfloat16(gelu_f(c0 * (&wa1.x)[i] + c1 * (&wb1.x)[i]
                                                   + c2 * (&wc1.x)[i] + (&bb1.x)[i]));
            *reinterpret_cast<short8*>(&hE[(size_t)r * EMBED + d]) = u.v;
        } else if (idx < t1) {
            unsigned j = idx - t0;
            unsigned r = j / (DEC_EMBED / 8), d = (j % (DEC_EMBED / 8)) * 8;
            float c0 = coords[r * 3 + 0], c1 = coords[r * 3 + 1], c2 = coords[r * 3 + 2];
            float4 wa0 = *reinterpret_cast<const float4*>(w1d + 0 * DEC_EMBED + d);
            float4 wa1 = *reinterpret_cast<const float4*>(w1d + 0 * DEC_EMBED + d + 4);
            float4 wb0 = *reinterpret_cast<const float4*>(w1d + 1 * DEC_EMBED + d);
            float4 wb1 = *reinterpret_cast<const float4*>(w1d + 1 * DEC_EMBED + d + 4);
            float4 wc0 = *reinterpret_cast<const float4*>(w1d + 2 * DEC_EMBED + d);
            float4 wc1 = *reinterpret_cast<const float4*>(w1d + 2 * DEC_EMBED + d + 4);
            float4 bb0 = *reinterpret_cast<const float4*>(b1d + d);
            float4 bb1 = *reinterpret_cast<const float4*>(b1d + d + 4);
            union { short8 v; __hip_bfloat16 h[8]; } u;
            #pragma unroll
            for (int i = 0; i < 4; ++i)
                u.h[i] = __float2bfloat16(gelu_f(c0 * (&wa0.x)[i] + c1 * (&wb0.x)[i]
                                               + c2 * (&wc0.x)[i] + (&bb0.x)[i]));
            #pragma unroll
            for (int i = 0; i < 4; ++i)
                u.h[4 + i] = __float2bfloat16(gelu_f(c0 * (&wa1.x)[i] + c1 * (&wb1.x)[i]
                                                   + c2 * (&wc1.x)[i] + (&bb1.x)[i]));
            *reinterpret_cast<short8*>(&hD[(size_t)r * DEC_EMBED + d]) = u.v;
        } else if (idx < t2) {
            int i = (int)(idx - t1);
            atomicAdd(&qcount[q[i]], 1);
            atomicAdd(&segcnt[seg[i]], 1);
        } else if (idx < t3) {
            unsigned j = idx - t2;
            reinterpret_cast<float4*>(out1)[j] =
                reinterpret_cast<const float4*>(sel)[j];
        } else {
            unsigned j = idx - t3;
            reinterpret_cast<float4*>(out2)[j] =
                reinterpret_cast<const float4*>(selc)[j];
        }
    }
}

// ---- both prefix sums in one launch ----

__global__ void prefix_both_kernel(const int* __restrict__ qcount, int* __restrict__ qoffs,
                                   int* __restrict__ qfill, int psize3,
                                   const int* __restrict__ segcnt, int* __restrict__ seg_offs,
                                   int* __restrict__ segfill, int num_seg) {
    const int* cnt; int* offs; int* fill; int n;
    if (blockIdx.x == 0) { cnt = qcount; offs = qoffs;    fill = qfill;   n = psize3; }
    else                 { cnt = segcnt; offs = seg_offs; fill = segfill; n = num_seg; }
    __shared__ int partial[NTHREADS];
    int t = threadIdx.x;
    int per = (n + NTHREADS - 1) / NTHREADS;
    int s = 0;
    for (int i = 0; i < per; ++i) {
        int idx = t * per + i;
        if (idx < n) s += cnt[idx];
    }
    partial[t] = s;
    __syncthreads();
    if (t == 0) {
        int run = 0;
        for (int i = 0; i < NTHREADS; ++i) { int v = partial[i]; partial[i] = run; run += v; }
    }
    __syncthreads();
    int run = partial[t];
    for (int i = 0; i < per; ++i) {
        int idx = t * per + i;
        if (idx < n) {
            offs[idx] = run;
            fill[idx] = run;
            run += cnt[idx];
        }
    }
    if (t == NTHREADS - 1) offs[n] = run;
}

// ---- fill: bucket-order records {sel[6]} + perm[segpos]=bucketpos ----

__global__ void fill_kernel(const int* __restrict__ q, const int* __restrict__ seg,
                            const float* __restrict__ sel,
                            int* __restrict__ qfill, int* __restrict__ segfill,
                            int* __restrict__ bucket, float* __restrict__ rec,
                            int* __restrict__ perm, int npts) {
    int i = blockIdx.x * blockDim.x + threadIdx.x;
    if (i < npts) {
        int pos = atomicAdd(&qfill[q[i]], 1);
        bucket[pos] = i;
        int sp = atomicAdd(&segfill[seg[i]], 1);
        if (rec) {
            perm[sp] = pos;
            const float2* s2 = reinterpret_cast<const float2*>(sel + (size_t)i * IN_CHANS);
            float2 a = s2[0], b = s2[1], c = s2[2];
            float4* rp = reinterpret_cast<float4*>(rec) + (size_t)pos * 2;
            rp[0] = make_float4(a.x, a.y, b.x, b.y);
            rp[1] = make_float4(c.x, c.y, 0.f, 0.f);
        }
    }
}

// ---- projection -> bf16 feats in BUCKET order; high occupancy ----
// 384 thr = 4 point-groups x 96; thread owns 8 consecutive dims.
// launch_bounds(384,8): 8 waves/EU -> ~5 blocks/CU resident (VGPR<=64).

__global__ __launch_bounds__(384, 8)
void project_store_kernel(const float* __restrict__ W,
                          const float* __restrict__ rec,
                          const int* __restrict__ qoffs,
                          __hip_bfloat16* __restrict__ feats, int psize3) {
    int qi = blockIdx.x;
    int t = threadIdx.x;          // 0..383
    int g  = t / 96;              // point-parity group 0..3
    int d8 = (t % 96) * 8;        // owned dims [d8, d8+8)
    const float* Wg = W + (size_t)qi * IN_CHANS * EMBED + d8;
    float4 wA[IN_CHANS], wB[IN_CHANS];
    #pragma unroll
    for (int c = 0; c < IN_CHANS; ++c) {
        wA[c] = *reinterpret_cast<const float4*>(Wg + c * EMBED);
        wB[c] = *reinterpret_cast<const float4*>(Wg + c * EMBED + 4);
    }

    __shared__ float4 buf[128];
    const float4* rp = reinterpret_cast<const float4*>(rec);
    int beg = qoffs[qi], end = qoffs[qi + 1];
    for (int base = beg; base < end; base += 64) {
        int chunk = min(64, end - base);
        __syncthreads();
        if (t < chunk * 2) buf[t] = rp[(size_t)base * 2 + t];
        __syncthreads();
        for (int pp = 0; pp < chunk; pp += 4) {
            int p = pp + g;
            if (p < chunk) {
                float4 ra = buf[2 * p];
                float4 rb = buf[2 * p + 1];
                union { short8 v; __hip_bfloat16 h[8]; } u;
                #pragma unroll
                for (int i = 0; i < 4; ++i) {
                    float f = ra.x * (&wA[0].x)[i] + ra.y * (&wA[1].x)[i]
                            + ra.z * (&wA[2].x)[i] + ra.w * (&wA[3].x)[i]
                            + rb.x * (&wA[4].x)[i] + rb.y * (&wA[5].x)[i];
                    u.h[i] = __float2bfloat16(f);
                }
                #pragma unroll
                for (int i = 0; i < 4; ++i) {
                    float f = ra.x * (&wB[0].x)[i] + ra.y * (&wB[1].x)[i]
                            + ra.z * (&wB[2].x)[i] + ra.w * (&wB[3].x)[i]
                            + rb.x * (&wB[4].x)[i] + rb.y * (&wB[5].x)[i];
                    u.h[4 + i] = __float2bfloat16(f);
                }
                *reinterpret_cast<short8*>(&feats[(size_t)(base + p) * EMBED + d8]) = u.v;
            }
        }
    }
}

// ---- one block (192 thr) per segment: gather rows via perm (16B loads), mean ----

__global__ void seg_reduce_kernel(const __hip_bfloat16* __restrict__ feats,
                                  const int* __restrict__ seg_offs,
                                  const int* __restrict__ perm,
                                  const int* __restrict__ pad_idx,
                                  float* __restrict__ out0) {
    int s = blockIdx.x;
    int t = threadIdx.x;          // 0..191
    int g  = t / 96;
    int ts = t % 96;
    int d8 = ts * 8;
    int beg = seg_offs[s], end = seg_offs[s + 1];
    int cnt = end - beg;
    __shared__ int rows[256];
    __shared__ float comb[96 * 8];
    for (int j = t; j < cnt; j += 192) rows[j] = perm[beg + j];
    __syncthreads();
    float a[8];
    #pragma unroll
    for (int i = 0; i < 8; ++i) a[i] = 0.f;
    for (int i = g; i < cnt; i += 2) {
        uint4_t v = *reinterpret_cast<const uint4_t*>(&feats[(size_t)rows[i] * EMBED + d8]);
        a[0] += __uint_as_float(v.x << 16);
        a[1] += __uint_as_float(v.x & 0xffff0000u);
        a[2] += __uint_as_float(v.y << 16);
        a[3] += __uint_as_float(v.y & 0xffff0000u);
        a[4] += __uint_as_float(v.z << 16);
        a[5] += __uint_as_float(v.z & 0xffff0000u);
        a[6] += __uint_as_float(v.w << 16);
        a[7] += __uint_as_float(v.w & 0xffff0000u);
    }
    if (g == 1) {
        #pragma unroll
        for (int i = 0; i < 8; ++i) comb[ts * 8 + i] = a[i];
    }
    __syncthreads();
    if (g == 0) {
        float inv = 1.0f / (float)max(cnt, 1);
        size_t j = (size_t)pad_idx[s];
        float4 o0, o1;
        #pragma unroll
        for (int i = 0; i < 4; ++i) (&o0.x)[i] = (a[i] + comb[ts * 8 + i]) * inv;
        #pragma unroll
        for (int i = 0; i < 4; ++i) (&o1.x)[i] = (a[4 + i] + comb[ts * 8 + 4 + i]) * inv;
        *reinterpret_cast<float4*>(&out0[j * EMBED + d8]) = o0;
        *reinterpret_cast<float4*>(&out0[j * EMBED + d8 + 4]) = o1;
    }
}

// ---- fallback path (small ws): atomic scatter ----

__global__ void project_kernel(const float* __restrict__ sel, const int* __restrict__ seg,
                               const int* __restrict__ pad_idx, const float* __restrict__ W,
                               const int* __restrict__ bucket, const int* __restrict__ qoffs,
                               float* __restrict__ out0) {
    int qi = blockIdx.x;
    __shared__ float Wl[IN_CHANS * EMBED];
    __shared__ float sel_l[64][IN_CHANS];
    __shared__ int   j_l[64];
    int t = threadIdx.x;
    const float* Wg = W + (size_t)qi * IN_CHANS * EMBED;
    for (int i = t; i < IN_CHANS * EMBED; i += NTHREADS) Wl[i] = Wg[i];
    int beg = qoffs[qi], end = qoffs[qi + 1];
    __syncthreads();
    for (int base = beg; base < end; base += 64) {
        int chunk = min(64, end - base);
        if (t < chunk) {
            int n = bucket[base + t];
            #pragma unroll
            for (int c = 0; c < IN_CHANS; ++c) sel_l[t][c] = sel[(size_t)n * IN_CHANS + c];
            j_l[t] = pad_idx[seg[n]];
        }
        __syncthreads();
        for (int p = 0; p < chunk; ++p) {
            float s0 = sel_l[p][0], s1 = sel_l[p][1], s2 = sel_l[p][2];
            float s3 = sel_l[p][3], s4 = sel_l[p][4], s5 = sel_l[p][5];
            size_t j = (size_t)j_l[p];
            #pragma unroll
            for (int r = 0; r < 3; ++r) {
                int d = r * NTHREADS + t;
                float f = s0 * Wl[0 * EMBED + d] + s1 * Wl[1 * EMBED + d]
                        + s2 * Wl[2 * EMBED + d] + s3 * Wl[3 * EMBED + d]
                        + s4 * Wl[4 * EMBED + d] + s5 * Wl[5 * EMBED + d];
                unsafeAtomicAdd(&out0[j * EMBED + d], f);
            }
        }
        __syncthreads();
    }
}

__global__ void finalize_kernel(const int* __restrict__ segcnt, const int* __restrict__ pad_idx,
                                float* __restrict__ out0, int num_seg) {
    int total = num_seg * EMBED;
    for (int idx = blockIdx.x * blockDim.x + threadIdx.x; idx < total;
         idx += gridDim.x * blockDim.x) {
        int i = idx / EMBED, d = idx % EMBED;
        int c = segcnt[i];
        float inv = 1.0f / (float)max(c, 1);
        out0[(size_t)pad_idx[i] * EMBED + d] *= inv;
    }
}

// ---- bf16 MFMA GEMM via LDS (m97 structure): out (+)= h @ w2 + b2 ----

__global__ __launch_bounds__(256, 4)
void gemm_lds_kernel(const __hip_bfloat16* __restrict__ hE,
                     const __hip_bfloat16* __restrict__ w2tE,
                     const float* __restrict__ b2e,
                     const __hip_bfloat16* __restrict__ hD,
                     const __hip_bfloat16* __restrict__ w2tD,
                     const float* __restrict__ b2d,
                     float* __restrict__ out0, float* __restrict__ out3,
                     int M, int nblkE) {
    int nblk = gridDim.x;
    int bid = blockIdx.x;
    int q8 = nblk >> 3, r8 = nblk & 7;
    int xcd = bid & 7, idx = bid >> 3;
    int bx = (xcd < r8 ? xcd * (q8 + 1) : r8 * (q8 + 1) + (xcd - r8) * q8) + idx;

    const short* A;
    const short* Bt;
    const float* b2;
    float* out;
    int N, K;
    bool accum;
    if (bx < nblkE) {
        A = (const short*)hE; Bt = (const short*)w2tE; b2 = b2e; out = out0;
        N = EMBED; K = EMBED; accum = true;
    } else {
        bx -= nblkE;
        A = (const short*)hD; Bt = (const short*)w2tD; b2 = b2d; out = out3;
        N = DEC_EMBED; K = DEC_EMBED; accum = false;
    }
    constexpr int BM = 128, BN = 64, BK = 32;
    int ctiles = N / BN;
    int rt = bx / ctiles, ct = bx % ctiles;

    __shared__ short Al[BM * BK];
    __shared__ short Bl[BN * BK];

    int t = threadIdx.x;
    int lane = t & 63;
    int w = t >> 6;
    int wr = w >> 1, wc = w & 1;
    int r0 = wr * 64;
    int c0 = wc * 32;

    int lrow = lane & 15;
    int kgrp = (lane >> 4) << 3;

    int oA = t * 16;
    int rowA0 = oA >> 6;
    int kkA  = (oA & 63) >> 1;
    int rowA1 = rowA0 + 64;
    int rowB = oA >> 6;

    int gA0 = rt * BM + rowA0; if (gA0 >= M) gA0 = M - 1;
    int gA1 = rt * BM + rowA1; if (gA1 >= M) gA1 = M - 1;
    const short* a0p = A + (size_t)gA0 * K + kkA;
    const short* a1p = A + (size_t)gA1 * K + kkA;
    const short* bp  = Bt + (size_t)(ct * BN + rowB) * K + kkA;
    short* la0 = &Al[t * 8];
    short* la1 = &Al[t * 8 + 2048];
    short* lb  = &Bl[t * 8];

    f32x4 acc[4][2];
    #pragma unroll
    for (int mi = 0; mi < 4; ++mi)
        #pragma unroll
        for (int ni = 0; ni < 2; ++ni) acc[mi][ni] = f32x4{0.f, 0.f, 0.f, 0.f};

    for (int k0 = 0; k0 < K; k0 += BK) {
        gload_lds16(a0p + k0, la0);
        gload_lds16(a1p + k0, la1);
        gload_lds16(bp + k0, lb);
        __syncthreads();
        short8 af[4], bf[2];
        #pragma unroll
        for (int mi = 0; mi < 4; ++mi)
            af[mi] = *reinterpret_cast<const short8*>(&Al[(r0 + mi * 16 + lrow) * BK + kgrp]);
        #pragma unroll
        for (int ni = 0; ni < 2; ++ni)
            bf[ni] = *reinterpret_cast<const short8*>(&Bl[(c0 + ni * 16 + lrow) * BK + kgrp]);
        #pragma unroll
        for (int mi = 0; mi < 4; ++mi)
            #pragma unroll
            for (int ni = 0; ni < 2; ++ni)
                acc[mi][ni] = __builtin_amdgcn_mfma_f32_16x16x32_bf16(af[mi], bf[ni],
                                                                      acc[mi][ni], 0, 0, 0);
        __syncthreads();
    }

    int rbase = (lane >> 4) << 2;
    #pragma unroll
    for (int ni = 0; ni < 2; ++ni) {
        int col = ct * BN + c0 + ni * 16 + lrow;
        float bb = b2[col];
        #pragma unroll
        for (int mi = 0; mi < 4; ++mi) {
            #pragma unroll
            for (int j = 0; j < 4; ++j) {
                int row = rt * BM + r0 + mi * 16 + rbase + j;
                if (row < M) {
                    size_t o = (size_t)row * N + col;
                    float v = acc[mi][ni][j] + bb;
                    if (accum) out[o] += v;
                    else       out[o]  = v;
                }
            }
        }
    }
}

// ---------------- host ----------------

extern "C" void kernel_launch(void* const* d_in, const int* in_sizes, int n_in,
                              void* d_out, int out_size, void* d_ws, size_t ws_size,
                              hipStream_t stream) {
    const float* sel_features = (const float*)d_in[0];
    const int*   q            = (const int*)d_in[1];
    const int*   seg          = (const int*)d_in[2];
    const int*   pad_idx      = (const int*)d_in[3];
    const float* coords       = (const float*)d_in[4];
    const float* sel_coors    = (const float*)d_in[5];
    const float* W            = (const float*)d_in[7];
    const float* w1e          = (const float*)d_in[8];
    const float* b1e          = (const float*)d_in[9];
    const float* w2e          = (const float*)d_in[10];
    const float* b2e          = (const float*)d_in[11];
    const float* w1d          = (const float*)d_in[12];
    const float* b1d          = (const float*)d_in[13];
    const float* w2d          = (const float*)d_in[14];
    const float* b2d          = (const float*)d_in[15];

    int npts    = in_sizes[1];
    int num_seg = in_sizes[3];
    int psize3  = in_sizes[7] / (IN_CHANS * EMBED);

    float* out  = (float*)d_out;
    float* out0 = out;                                       // [num_seg, 768]
    float* out1 = out0 + (size_t)num_seg * EMBED;            // sel_features copy
    float* out2 = out1 + (size_t)npts * IN_CHANS;            // sel_coors copy
    float* out3 = out2 + (size_t)npts * 3;                   // [num_seg, 512]

    // ws layout (big): feats | hE hD w2tE w2tD | rec | ints
    size_t feats_elems = (size_t)npts * EMBED;
    size_t mlp_elems = (size_t)num_seg * EMBED + (size_t)num_seg * DEC_EMBED
                     + (size_t)EMBED * EMBED + (size_t)DEC_EMBED * DEC_EMBED;
    size_t rec_bytes = (size_t)npts * 32;
    size_t n_ints = (size_t)psize3 * 2 + 1 + (size_t)num_seg * 2 + 1
                  + (size_t)npts * 2 + 16;
    size_t need_big = (feats_elems + mlp_elems) * 2 + rec_bytes + n_ints * 4;
    bool big = ws_size >= need_big;

    char* wsb = (char*)d_ws;
    __hip_bfloat16* feats = (__hip_bfloat16*)wsb;
    __hip_bfloat16* hE   = big ? feats + feats_elems : (__hip_bfloat16*)wsb;
    __hip_bfloat16* hD   = hE + (size_t)num_seg * EMBED;
    __hip_bfloat16* w2tE = hD + (size_t)num_seg * DEC_EMBED;
    __hip_bfloat16* w2tD = w2tE + (size_t)EMBED * EMBED;
    float* rec   = big ? (float*)(w2tD + (size_t)DEC_EMBED * DEC_EMBED) : nullptr;
    int* wsi     = big ? (int*)((char*)rec + rec_bytes)
                       : (int*)(w2tD + (size_t)DEC_EMBED * DEC_EMBED);
    int* qcount  = wsi;                       // psize3
    int* segcnt  = qcount + psize3;           // num_seg
    int* qoffs   = segcnt + num_seg;          // psize3+1
    int* qfill   = qoffs + psize3 + 1;        // psize3
    int* seg_offs= qfill + psize3;            // num_seg+1
    int* segfill = seg_offs + num_seg + 1;    // num_seg
    int* bucket  = segfill + num_seg;         // npts
    int* perm    = bucket + npts;             // npts

    hipMemsetAsync(qcount, 0, sizeof(int) * (size_t)(psize3 + num_seg), stream);

    int hcBlocks = 2048;
    int ntE = (EMBED / 32) * (EMBED / 32);
    int ntD = (DEC_EMBED / 32) * (DEC_EMBED / 32);
    hc_kernel<<<hcBlocks + ntE + ntD, NTHREADS, 0, stream>>>(
        coords, w1e, b1e, w1d, b1d, q, seg, sel_features, sel_coors,
        w2e, w2d, hE, hD, w2tE, w2tD, qcount, segcnt, out1, out2,
        hcBlocks, num_seg, npts);
    prefix_both_kernel<<<2, NTHREADS, 0, stream>>>(qcount, qoffs, qfill, psize3,
                                                   segcnt, seg_offs, segfill, num_seg);
    int pb = (npts + NTHREADS - 1) / NTHREADS;
    fill_kernel<<<pb, NTHREADS, 0, stream>>>(q, seg, sel_features, qfill, segfill,
                                             bucket, rec, perm, npts);

    if (big) {
        project_store_kernel<<<psize3, 384, 0, stream>>>(W, rec, qoffs, feats, psize3);
        seg_reduce_kernel<<<num_seg, 192, 0, stream>>>(feats, seg_offs, perm,
                                                       pad_idx, out0);
    } else {
        hipMemsetAsync(out0, 0, sizeof(float) * (size_t)num_seg * EMBED, stream);
        project_kernel<<<psize3, NTHREADS, 0, stream>>>(sel_features, seg, pad_idx, W,
                                                        bucket, qoffs, out0);
        finalize_kernel<<<2048, NTHREADS, 0, stream>>>(segcnt, pad_idx, out0, num_seg);
    }

    int rtiles = (num_seg + 127) / 128;
    int nblkE = rtiles * (EMBED / 64);
    int nblkD = rtiles * (DEC_EMBED / 64);
    gemm_lds_kernel<<<nblkE + nblkD, NTHREADS, 0, stream>>>(hE, w2tE, b2e, hD, w2tD, b2d,
                                                            out0, out3, num_seg, nblkE);
}

// Round 15
// 169.465 us; speedup vs baseline: 1.1446x; 1.1446x over previous
//
#include <hip/hip_runtime.h>
#include <hip/hip_bf16.h>
#include <cmath>

#define NTHREADS 256

constexpr int IN_CHANS = 6;
constexpr int EMBED = 768;
constexpr int DEC_EMBED = 512;

typedef __attribute__((ext_vector_type(8))) short short8;
typedef __attribute__((ext_vector_type(4))) short short4_t;
typedef __attribute__((ext_vector_type(4))) float f32x4;
typedef __attribute__((ext_vector_type(4))) unsigned int uint4_t;

__device__ __forceinline__ void gload_lds16(const short* g, short* l) {
    __builtin_amdgcn_global_load_lds((const __attribute__((address_space(1))) void*)g,
                                     (__attribute__((address_space(3))) void*)l, 16, 0, 0);
}

__device__ __forceinline__ float gelu_f(float x) {
    return 0.5f * x * (1.0f + erff(x * 0.70710678118654752f));
}

// ---- fused: h=gelu(coords@w1+b1) bf16 + counts + copies + w2 transpose ----

__global__ void hc_kernel(const float* __restrict__ coords,
                          const float* __restrict__ w1e, const float* __restrict__ b1e,
                          const float* __restrict__ w1d, const float* __restrict__ b1d,
                          const int* __restrict__ q, const int* __restrict__ seg,
                          const float* __restrict__ sel, const float* __restrict__ selc,
                          const float* __restrict__ w2e, const float* __restrict__ w2d,
                          __hip_bfloat16* __restrict__ hE, __hip_bfloat16* __restrict__ hD,
                          __hip_bfloat16* __restrict__ w2tE, __hip_bfloat16* __restrict__ w2tD,
                          int* __restrict__ qcount, int* __restrict__ segcnt,
                          float* __restrict__ out1, float* __restrict__ out2,
                          int hcBlocks, int num_seg, int npts) {
    __shared__ float tile[32][33];
    if ((int)blockIdx.x >= hcBlocks) {
        int b = blockIdx.x - hcBlocks;
        const float* src; __hip_bfloat16* dst; int n;
        const int ntE = (EMBED / 32) * (EMBED / 32);
        if (b < ntE) { src = w2e; dst = w2tE; n = EMBED; }
        else         { b -= ntE; src = w2d; dst = w2tD; n = DEC_EMBED; }
        int tpr = n / 32;
        int tr = b / tpr, tc = b % tpr;
        int tx = threadIdx.x & 31, ty = threadIdx.x >> 5;
        #pragma unroll
        for (int i = 0; i < 4; ++i)
            tile[ty + 8 * i][tx] = src[(size_t)(tr * 32 + ty + 8 * i) * n + tc * 32 + tx];
        __syncthreads();
        #pragma unroll
        for (int i = 0; i < 4; ++i)
            dst[(size_t)(tc * 32 + ty + 8 * i) * n + tr * 32 + tx] =
                __float2bfloat16(tile[tx][ty + 8 * i]);
        return;
    }
    const unsigned nE8 = (unsigned)num_seg * (EMBED / 8);
    const unsigned nD8 = (unsigned)num_seg * (DEC_EMBED / 8);
    const unsigned t0 = nE8;
    const unsigned t1 = t0 + nD8;
    const unsigned t2 = t1 + (unsigned)npts;                 // counts
    const unsigned n14 = (unsigned)npts * IN_CHANS / 4;      // out1 float4s
    const unsigned t3 = t2 + n14;
    const unsigned n24 = (unsigned)npts * 3 / 4;             // out2 float4s
    const unsigned t4 = t3 + n24;
    const unsigned stride = (unsigned)hcBlocks * blockDim.x;
    for (unsigned idx = blockIdx.x * blockDim.x + threadIdx.x; idx < t4; idx += stride) {
        if (idx < t0) {
            unsigned r = idx / (EMBED / 8), d = (idx % (EMBED / 8)) * 8;
            float c0 = coords[r * 3 + 0], c1 = coords[r * 3 + 1], c2 = coords[r * 3 + 2];
            float4 wa0 = *reinterpret_cast<const float4*>(w1e + 0 * EMBED + d);
            float4 wa1 = *reinterpret_cast<const float4*>(w1e + 0 * EMBED + d + 4);
            float4 wb0 = *reinterpret_cast<const float4*>(w1e + 1 * EMBED + d);
            float4 wb1 = *reinterpret_cast<const float4*>(w1e + 1 * EMBED + d + 4);
            float4 wc0 = *reinterpret_cast<const float4*>(w1e + 2 * EMBED + d);
            float4 wc1 = *reinterpret_cast<const float4*>(w1e + 2 * EMBED + d + 4);
            float4 bb0 = *reinterpret_cast<const float4*>(b1e + d);
            float4 bb1 = *reinterpret_cast<const float4*>(b1e + d + 4);
            union { short8 v; __hip_bfloat16 h[8]; } u;
            #pragma unroll
            for (int i = 0; i < 4; ++i)
                u.h[i] = __float2bfloat16(gelu_f(c0 * (&wa0.x)[i] + c1 * (&wb0.x)[i]
                                               + c2 * (&wc0.x)[i] + (&bb0.x)[i]));
            #pragma unroll
            for (int i = 0; i < 4; ++i)
                u.h[4 + i] = __float2bfloat16(gelu_f(c0 * (&wa1.x)[i] + c1 * (&wb1.x)[i]
                                                   + c2 * (&wc1.x)[i] + (&bb1.x)[i]));
            *reinterpret_cast<short8*>(&hE[(size_t)r * EMBED + d]) = u.v;
        } else if (idx < t1) {
            unsigned j = idx - t0;
            unsigned r = j / (DEC_EMBED / 8), d = (j % (DEC_EMBED / 8)) * 8;
            float c0 = coords[r * 3 + 0], c1 = coords[r * 3 + 1], c2 = coords[r * 3 + 2];
            float4 wa0 = *reinterpret_cast<const float4*>(w1d + 0 * DEC_EMBED + d);
            float4 wa1 = *reinterpret_cast<const float4*>(w1d + 0 * DEC_EMBED + d + 4);
            float4 wb0 = *reinterpret_cast<const float4*>(w1d + 1 * DEC_EMBED + d);
            float4 wb1 = *reinterpret_cast<const float4*>(w1d + 1 * DEC_EMBED + d + 4);
            float4 wc0 = *reinterpret_cast<const float4*>(w1d + 2 * DEC_EMBED + d);
            float4 wc1 = *reinterpret_cast<const float4*>(w1d + 2 * DEC_EMBED + d + 4);
            float4 bb0 = *reinterpret_cast<const float4*>(b1d + d);
            float4 bb1 = *reinterpret_cast<const float4*>(b1d + d + 4);
            union { short8 v; __hip_bfloat16 h[8]; } u;
            #pragma unroll
            for (int i = 0; i < 4; ++i)
                u.h[i] = __float2bfloat16(gelu_f(c0 * (&wa0.x)[i] + c1 * (&wb0.x)[i]
                                               + c2 * (&wc0.x)[i] + (&bb0.x)[i]));
            #pragma unroll
            for (int i = 0; i < 4; ++i)
                u.h[4 + i] = __float2bfloat16(gelu_f(c0 * (&wa1.x)[i] + c1 * (&wb1.x)[i]
                                                   + c2 * (&wc1.x)[i] + (&bb1.x)[i]));
            *reinterpret_cast<short8*>(&hD[(size_t)r * DEC_EMBED + d]) = u.v;
        } else if (idx < t2) {
            int i = (int)(idx - t1);
            atomicAdd(&qcount[q[i]], 1);
            atomicAdd(&segcnt[seg[i]], 1);
        } else if (idx < t3) {
            unsigned j = idx - t2;
            reinterpret_cast<float4*>(out1)[j] =
                reinterpret_cast<const float4*>(sel)[j];
        } else {
            unsigned j = idx - t3;
            reinterpret_cast<float4*>(out2)[j] =
                reinterpret_cast<const float4*>(selc)[j];
        }
    }
}

// ---- both prefix sums in one launch ----

__global__ void prefix_both_kernel(const int* __restrict__ qcount, int* __restrict__ qoffs,
                                   int* __restrict__ qfill, int psize3,
                                   const int* __restrict__ segcnt, int* __restrict__ seg_offs,
                                   int* __restrict__ segfill, int num_seg) {
    const int* cnt; int* offs; int* fill; int n;
    if (blockIdx.x == 0) { cnt = qcount; offs = qoffs;    fill = qfill;   n = psize3; }
    else                 { cnt = segcnt; offs = seg_offs; fill = segfill; n = num_seg; }
    __shared__ int partial[NTHREADS];
    int t = threadIdx.x;
    int per = (n + NTHREADS - 1) / NTHREADS;
    int s = 0;
    for (int i = 0; i < per; ++i) {
        int idx = t * per + i;
        if (idx < n) s += cnt[idx];
    }
    partial[t] = s;
    __syncthreads();
    if (t == 0) {
        int run = 0;
        for (int i = 0; i < NTHREADS; ++i) { int v = partial[i]; partial[i] = run; run += v; }
    }
    __syncthreads();
    int run = partial[t];
    for (int i = 0; i < per; ++i) {
        int idx = t * per + i;
        if (idx < n) {
            offs[idx] = run;
            fill[idx] = run;
            run += cnt[idx];
        }
    }
    if (t == NTHREADS - 1) offs[n] = run;
}

// ---- fill: bucket-order records {sel[6]} + perm[segpos]=bucketpos ----

__global__ void fill_kernel(const int* __restrict__ q, const int* __restrict__ seg,
                            const float* __restrict__ sel,
                            int* __restrict__ qfill, int* __restrict__ segfill,
                            int* __restrict__ bucket, float* __restrict__ rec,
                            int* __restrict__ perm, int npts) {
    int i = blockIdx.x * blockDim.x + threadIdx.x;
    if (i < npts) {
        int pos = atomicAdd(&qfill[q[i]], 1);
        bucket[pos] = i;
        int sp = atomicAdd(&segfill[seg[i]], 1);
        if (rec) {
            perm[sp] = pos;
            const float2* s2 = reinterpret_cast<const float2*>(sel + (size_t)i * IN_CHANS);
            float2 a = s2[0], b = s2[1], c = s2[2];
            float4* rp = reinterpret_cast<float4*>(rec) + (size_t)pos * 2;
            rp[0] = make_float4(a.x, a.y, b.x, b.y);
            rp[1] = make_float4(c.x, c.y, 0.f, 0.f);
        }
    }
}

// ---- projection -> bf16 feats in BUCKET order ----
// 384 thr = 4 point-groups x 96; thread owns 8 consecutive dims.
// launch_bounds(384,6): 6 waves/EU -> 4 blocks/CU, VGPR cap ~80 (no spill).

__global__ __launch_bounds__(384, 6)
void project_store_kernel(const float* __restrict__ W,
                          const float* __restrict__ rec,
                          const int* __restrict__ qoffs,
                          __hip_bfloat16* __restrict__ feats, int psize3) {
    int qi = blockIdx.x;
    int t = threadIdx.x;          // 0..383
    int g  = t / 96;              // point-parity group 0..3
    int d8 = (t % 96) * 8;        // owned dims [d8, d8+8)
    const float* Wg = W + (size_t)qi * IN_CHANS * EMBED + d8;
    float4 wA[IN_CHANS], wB[IN_CHANS];
    #pragma unroll
    for (int c = 0; c < IN_CHANS; ++c) {
        wA[c] = *reinterpret_cast<const float4*>(Wg + c * EMBED);
        wB[c] = *reinterpret_cast<const float4*>(Wg + c * EMBED + 4);
    }

    __shared__ float4 buf[128];
    const float4* rp = reinterpret_cast<const float4*>(rec);
    int beg = qoffs[qi], end = qoffs[qi + 1];
    for (int base = beg; base < end; base += 64) {
        int chunk = min(64, end - base);
        __syncthreads();
        if (t < chunk * 2) buf[t] = rp[(size_t)base * 2 + t];
        __syncthreads();
        for (int pp = 0; pp < chunk; pp += 4) {
            int p = pp + g;
            if (p < chunk) {
                float4 ra = buf[2 * p];
                float4 rb = buf[2 * p + 1];
                union { short8 v; __hip_bfloat16 h[8]; } u;
                #pragma unroll
                for (int i = 0; i < 4; ++i) {
                    float f = ra.x * (&wA[0].x)[i] + ra.y * (&wA[1].x)[i]
                            + ra.z * (&wA[2].x)[i] + ra.w * (&wA[3].x)[i]
                            + rb.x * (&wA[4].x)[i] + rb.y * (&wA[5].x)[i];
                    u.h[i] = __float2bfloat16(f);
                }
                #pragma unroll
                for (int i = 0; i < 4; ++i) {
                    float f = ra.x * (&wB[0].x)[i] + ra.y * (&wB[1].x)[i]
                            + ra.z * (&wB[2].x)[i] + ra.w * (&wB[3].x)[i]
                            + rb.x * (&wB[4].x)[i] + rb.y * (&wB[5].x)[i];
                    u.h[4 + i] = __float2bfloat16(f);
                }
                *reinterpret_cast<short8*>(&feats[(size_t)(base + p) * EMBED + d8]) = u.v;
            }
        }
    }
}

// ---- one block (192 thr) per segment: gather rows via perm (16B loads), mean ----

__global__ void seg_reduce_kernel(const __hip_bfloat16* __restrict__ feats,
                                  const int* __restrict__ seg_offs,
                                  const int* __restrict__ perm,
                                  const int* __restrict__ pad_idx,
                                  float* __restrict__ out0) {
    int s = blockIdx.x;
    int t = threadIdx.x;          // 0..191
    int g  = t / 96;
    int ts = t % 96;
    int d8 = ts * 8;
    int beg = seg_offs[s], end = seg_offs[s + 1];
    int cnt = end - beg;
    __shared__ int rows[256];
    __shared__ float comb[96 * 8];
    for (int j = t; j < cnt; j += 192) rows[j] = perm[beg + j];
    __syncthreads();
    float a[8];
    #pragma unroll
    for (int i = 0; i < 8; ++i) a[i] = 0.f;
    for (int i = g; i < cnt; i += 2) {
        uint4_t v = *reinterpret_cast<const uint4_t*>(&feats[(size_t)rows[i] * EMBED + d8]);
        a[0] += __uint_as_float(v.x << 16);
        a[1] += __uint_as_float(v.x & 0xffff0000u);
        a[2] += __uint_as_float(v.y << 16);
        a[3] += __uint_as_float(v.y & 0xffff0000u);
        a[4] += __uint_as_float(v.z << 16);
        a[5] += __uint_as_float(v.z & 0xffff0000u);
        a[6] += __uint_as_float(v.w << 16);
        a[7] += __uint_as_float(v.w & 0xffff0000u);
    }
    if (g == 1) {
        #pragma unroll
        for (int i = 0; i < 8; ++i) comb[ts * 8 + i] = a[i];
    }
    __syncthreads();
    if (g == 0) {
        float inv = 1.0f / (float)max(cnt, 1);
        size_t j = (size_t)pad_idx[s];
        float4 o0, o1;
        #pragma unroll
        for (int i = 0; i < 4; ++i) (&o0.x)[i] = (a[i] + comb[ts * 8 + i]) * inv;
        #pragma unroll
        for (int i = 0; i < 4; ++i) (&o1.x)[i] = (a[4 + i] + comb[ts * 8 + 4 + i]) * inv;
        *reinterpret_cast<float4*>(&out0[j * EMBED + d8]) = o0;
        *reinterpret_cast<float4*>(&out0[j * EMBED + d8 + 4]) = o1;
    }
}

// ---- fallback path (small ws): atomic scatter ----

__global__ void project_kernel(const float* __restrict__ sel, const int* __restrict__ seg,
                               const int* __restrict__ pad_idx, const float* __restrict__ W,
                               const int* __restrict__ bucket, const int* __restrict__ qoffs,
                               float* __restrict__ out0) {
    int qi = blockIdx.x;
    __shared__ float Wl[IN_CHANS * EMBED];
    __shared__ float sel_l[64][IN_CHANS];
    __shared__ int   j_l[64];
    int t = threadIdx.x;
    const float* Wg = W + (size_t)qi * IN_CHANS * EMBED;
    for (int i = t; i < IN_CHANS * EMBED; i += NTHREADS) Wl[i] = Wg[i];
    int beg = qoffs[qi], end = qoffs[qi + 1];
    __syncthreads();
    for (int base = beg; base < end; base += 64) {
        int chunk = min(64, end - base);
        if (t < chunk) {
            int n = bucket[base + t];
            #pragma unroll
            for (int c = 0; c < IN_CHANS; ++c) sel_l[t][c] = sel[(size_t)n * IN_CHANS + c];
            j_l[t] = pad_idx[seg[n]];
        }
        __syncthreads();
        for (int p = 0; p < chunk; ++p) {
            float s0 = sel_l[p][0], s1 = sel_l[p][1], s2 = sel_l[p][2];
            float s3 = sel_l[p][3], s4 = sel_l[p][4], s5 = sel_l[p][5];
            size_t j = (size_t)j_l[p];
            #pragma unroll
            for (int r = 0; r < 3; ++r) {
                int d = r * NTHREADS + t;
                float f = s0 * Wl[0 * EMBED + d] + s1 * Wl[1 * EMBED + d]
                        + s2 * Wl[2 * EMBED + d] + s3 * Wl[3 * EMBED + d]
                        + s4 * Wl[4 * EMBED + d] + s5 * Wl[5 * EMBED + d];
                unsafeAtomicAdd(&out0[j * EMBED + d], f);
            }
        }
        __syncthreads();
    }
}

__global__ void finalize_kernel(const int* __restrict__ segcnt, const int* __restrict__ pad_idx,
                                float* __restrict__ out0, int num_seg) {
    int total = num_seg * EMBED;
    for (int idx = blockIdx.x * blockDim.x + threadIdx.x; idx < total;
         idx += gridDim.x * blockDim.x) {
        int i = idx / EMBED, d = idx % EMBED;
        int c = segcnt[i];
        float inv = 1.0f / (float)max(c, 1);
        out0[(size_t)pad_idx[i] * EMBED + d] *= inv;
    }
}

// ---- bf16 MFMA GEMM via LDS (m97 structure): out (+)= h @ w2 + b2 ----

__global__ __launch_bounds__(256, 4)
void gemm_lds_kernel(const __hip_bfloat16* __restrict__ hE,
                     const __hip_bfloat16* __restrict__ w2tE,
                     const float* __restrict__ b2e,
                     const __hip_bfloat16* __restrict__ hD,
                     const __hip_bfloat16* __restrict__ w2tD,
                     const float* __restrict__ b2d,
                     float* __restrict__ out0, float* __restrict__ out3,
                     int M, int nblkE) {
    int nblk = gridDim.x;
    int bid = blockIdx.x;
    int q8 = nblk >> 3, r8 = nblk & 7;
    int xcd = bid & 7, idx = bid >> 3;
    int bx = (xcd < r8 ? xcd * (q8 + 1) : r8 * (q8 + 1) + (xcd - r8) * q8) + idx;

    const short* A;
    const short* Bt;
    const float* b2;
    float* out;
    int N, K;
    bool accum;
    if (bx < nblkE) {
        A = (const short*)hE; Bt = (const short*)w2tE; b2 = b2e; out = out0;
        N = EMBED; K = EMBED; accum = true;
    } else {
        bx -= nblkE;
        A = (const short*)hD; Bt = (const short*)w2tD; b2 = b2d; out = out3;
        N = DEC_EMBED; K = DEC_EMBED; accum = false;
    }
    constexpr int BM = 128, BN = 64, BK = 32;
    int ctiles = N / BN;
    int rt = bx / ctiles, ct = bx % ctiles;

    __shared__ short Al[BM * BK];
    __shared__ short Bl[BN * BK];

    int t = threadIdx.x;
    int lane = t & 63;
    int w = t >> 6;
    int wr = w >> 1, wc = w & 1;
    int r0 = wr * 64;
    int c0 = wc * 32;

    int lrow = lane & 15;
    int kgrp = (lane >> 4) << 3;

    int oA = t * 16;
    int rowA0 = oA >> 6;
    int kkA  = (oA & 63) >> 1;
    int rowA1 = rowA0 + 64;
    int rowB = oA >> 6;

    int gA0 = rt * BM + rowA0; if (gA0 >= M) gA0 = M - 1;
    int gA1 = rt * BM + rowA1; if (gA1 >= M) gA1 = M - 1;
    const short* a0p = A + (size_t)gA0 * K + kkA;
    const short* a1p = A + (size_t)gA1 * K + kkA;
    const short* bp  = Bt + (size_t)(ct * BN + rowB) * K + kkA;
    short* la0 = &Al[t * 8];
    short* la1 = &Al[t * 8 + 2048];
    short* lb  = &Bl[t * 8];

    f32x4 acc[4][2];
    #pragma unroll
    for (int mi = 0; mi < 4; ++mi)
        #pragma unroll
        for (int ni = 0; ni < 2; ++ni) acc[mi][ni] = f32x4{0.f, 0.f, 0.f, 0.f};

    for (int k0 = 0; k0 < K; k0 += BK) {
        gload_lds16(a0p + k0, la0);
        gload_lds16(a1p + k0, la1);
        gload_lds16(bp + k0, lb);
        __syncthreads();
        short8 af[4], bf[2];
        #pragma unroll
        for (int mi = 0; mi < 4; ++mi)
            af[mi] = *reinterpret_cast<const short8*>(&Al[(r0 + mi * 16 + lrow) * BK + kgrp]);
        #pragma unroll
        for (int ni = 0; ni < 2; ++ni)
            bf[ni] = *reinterpret_cast<const short8*>(&Bl[(c0 + ni * 16 + lrow) * BK + kgrp]);
        #pragma unroll
        for (int mi = 0; mi < 4; ++mi)
            #pragma unroll
            for (int ni = 0; ni < 2; ++ni)
                acc[mi][ni] = __builtin_amdgcn_mfma_f32_16x16x32_bf16(af[mi], bf[ni],
                                                                      acc[mi][ni], 0, 0, 0);
        __syncthreads();
    }

    int rbase = (lane >> 4) << 2;
    #pragma unroll
    for (int ni = 0; ni < 2; ++ni) {
        int col = ct * BN + c0 + ni * 16 + lrow;
        float bb = b2[col];
        #pragma unroll
        for (int mi = 0; mi < 4; ++mi) {
            #pragma unroll
            for (int j = 0; j < 4; ++j) {
                int row = rt * BM + r0 + mi * 16 + rbase + j;
                if (row < M) {
                    size_t o = (size_t)row * N + col;
                    float v = acc[mi][ni][j] + bb;
                    if (accum) out[o] += v;
                    else       out[o]  = v;
                }
            }
        }
    }
}

// ---------------- host ----------------

extern "C" void kernel_launch(void* const* d_in, const int* in_sizes, int n_in,
                              void* d_out, int out_size, void* d_ws, size_t ws_size,
                              hipStream_t stream) {
    const float* sel_features = (const float*)d_in[0];
    const int*   q            = (const int*)d_in[1];
    const int*   seg          = (const int*)d_in[2];
    const int*   pad_idx      = (const int*)d_in[3];
    const float* coords       = (const float*)d_in[4];
    const float* sel_coors    = (const float*)d_in[5];
    const float* W            = (const float*)d_in[7];
    const float* w1e          = (const float*)d_in[8];
    const float* b1e          = (const float*)d_in[9];
    const float* w2e          = (const float*)d_in[10];
    const float* b2e          = (const float*)d_in[11];
    const float* w1d          = (const float*)d_in[12];
    const float* b1d          = (const float*)d_in[13];
    const float* w2d          = (const float*)d_in[14];
    const float* b2d          = (const float*)d_in[15];

    int npts    = in_sizes[1];
    int num_seg = in_sizes[3];
    int psize3  = in_sizes[7] / (IN_CHANS * EMBED);

    float* out  = (float*)d_out;
    float* out0 = out;                                       // [num_seg, 768]
    float* out1 = out0 + (size_t)num_seg * EMBED;            // sel_features copy
    float* out2 = out1 + (size_t)npts * IN_CHANS;            // sel_coors copy
    float* out3 = out2 + (size_t)npts * 3;                   // [num_seg, 512]

    // ws layout (big): feats | hE hD w2tE w2tD | rec | ints
    size_t feats_elems = (size_t)npts * EMBED;
    size_t mlp_elems = (size_t)num_seg * EMBED + (size_t)num_seg * DEC_EMBED
                     + (size_t)EMBED * EMBED + (size_t)DEC_EMBED * DEC_EMBED;
    size_t rec_bytes = (size_t)npts * 32;
    size_t n_ints = (size_t)psize3 * 2 + 1 + (size_t)num_seg * 2 + 1
                  + (size_t)npts * 2 + 16;
    size_t need_big = (feats_elems + mlp_elems) * 2 + rec_bytes + n_ints * 4;
    bool big = ws_size >= need_big;

    char* wsb = (char*)d_ws;
    __hip_bfloat16* feats = (__hip_bfloat16*)wsb;
    __hip_bfloat16* hE   = big ? feats + feats_elems : (__hip_bfloat16*)wsb;
    __hip_bfloat16* hD   = hE + (size_t)num_seg * EMBED;
    __hip_bfloat16* w2tE = hD + (size_t)num_seg * DEC_EMBED;
    __hip_bfloat16* w2tD = w2tE + (size_t)EMBED * EMBED;
    float* rec   = big ? (float*)(w2tD + (size_t)DEC_EMBED * DEC_EMBED) : nullptr;
    int* wsi     = big ? (int*)((char*)rec + rec_bytes)
                       : (int*)(w2tD + (size_t)DEC_EMBED * DEC_EMBED);
    int* qcount  = wsi;                       // psize3
    int* segcnt  = qcount + psize3;           // num_seg
    int* qoffs   = segcnt + num_seg;          // psize3+1
    int* qfill   = qoffs + psize3 + 1;        // psize3
    int* seg_offs= qfill + psize3;            // num_seg+1
    int* segfill = seg_offs + num_seg + 1;    // num_seg
    int* bucket  = segfill + num_seg;         // npts
    int* perm    = bucket + npts;             // npts

    hipMemsetAsync(qcount, 0, sizeof(int) * (size_t)(psize3 + num_seg), stream);

    int hcBlocks = 2048;
    int ntE = (EMBED / 32) * (EMBED / 32);
    int ntD = (DEC_EMBED / 32) * (DEC_EMBED / 32);
    hc_kernel<<<hcBlocks + ntE + ntD, NTHREADS, 0, stream>>>(
        coords, w1e, b1e, w1d, b1d, q, seg, sel_features, sel_coors,
        w2e, w2d, hE, hD, w2tE, w2tD, qcount, segcnt, out1, out2,
        hcBlocks, num_seg, npts);
    prefix_both_kernel<<<2, NTHREADS, 0, stream>>>(qcount, qoffs, qfill, psize3,
                                                   segcnt, seg_offs, segfill, num_seg);
    int pb = (npts + NTHREADS - 1) / NTHREADS;
    fill_kernel<<<pb, NTHREADS, 0, stream>>>(q, seg, sel_features, qfill, segfill,
                                             bucket, rec, perm, npts);

    if (big) {
        project_store_kernel<<<psize3, 384, 0, stream>>>(W, rec, qoffs, feats, psize3);
        seg_reduce_kernel<<<num_seg, 192, 0, stream>>>(feats, seg_offs, perm,
                                                       pad_idx, out0);
    } else {
        hipMemsetAsync(out0, 0, sizeof(float) * (size_t)num_seg * EMBED, stream);
        project_kernel<<<psize3, NTHREADS, 0, stream>>>(sel_features, seg, pad_idx, W,
                                                        bucket, qoffs, out0);
        finalize_kernel<<<2048, NTHREADS, 0, stream>>>(segcnt, pad_idx, out0, num_seg);
    }

    int rtiles = (num_seg + 127) / 128;
    int nblkE = rtiles * (EMBED / 64);
    int nblkD = rtiles * (DEC_EMBED / 64);
    gemm_lds_kernel<<<nblkE + nblkD, NTHREADS, 0, stream>>>(hE, w2tE, b2e, hD, w2tD, b2d,
                                                            out0, out3, num_seg, nblkE);
}

// Round 16
// 102.549 us; speedup vs baseline: 1.8915x; 1.6525x over previous
//
#include <hip/hip_runtime.h>
#include <hip/hip_bf16.h>
#include <cmath>

#define NTHREADS 256

constexpr int IN_CHANS = 6;
constexpr int EMBED = 768;
constexpr int DEC_EMBED = 512;

typedef __attribute__((ext_vector_type(8))) short short8;
typedef __attribute__((ext_vector_type(4))) short short4_t;
typedef __attribute__((ext_vector_type(4))) float f32x4;
typedef __attribute__((ext_vector_type(4))) unsigned int uint4_t;

__device__ __forceinline__ void gload_lds16(const short* g, short* l) {
    __builtin_amdgcn_global_load_lds((const __attribute__((address_space(1))) void*)g,
                                     (__attribute__((address_space(3))) void*)l, 16, 0, 0);
}

__device__ __forceinline__ float gelu_f(float x) {
    return 0.5f * x * (1.0f + erff(x * 0.70710678118654752f));
}

// ---- fused: h=gelu(coords@w1+b1) bf16 + counts + copies + w2 transpose
//      + W==1 check (sets notones flag) ----

__global__ void hc_kernel(const float* __restrict__ coords,
                          const float* __restrict__ w1e, const float* __restrict__ b1e,
                          const float* __restrict__ w1d, const float* __restrict__ b1d,
                          const int* __restrict__ q, const int* __restrict__ seg,
                          const float* __restrict__ sel, const float* __restrict__ selc,
                          const float* __restrict__ w2e, const float* __restrict__ w2d,
                          const float* __restrict__ Wproj,
                          __hip_bfloat16* __restrict__ hE, __hip_bfloat16* __restrict__ hD,
                          __hip_bfloat16* __restrict__ w2tE, __hip_bfloat16* __restrict__ w2tD,
                          int* __restrict__ qcount, int* __restrict__ segcnt,
                          int* __restrict__ notones,
                          float* __restrict__ out1, float* __restrict__ out2,
                          int hcBlocks, int num_seg, int npts, int psize3) {
    __shared__ float tile[32][33];
    if ((int)blockIdx.x >= hcBlocks) {
        int b = blockIdx.x - hcBlocks;
        const float* src; __hip_bfloat16* dst; int n;
        const int ntE = (EMBED / 32) * (EMBED / 32);
        if (b < ntE) { src = w2e; dst = w2tE; n = EMBED; }
        else         { b -= ntE; src = w2d; dst = w2tD; n = DEC_EMBED; }
        int tpr = n / 32;
        int tr = b / tpr, tc = b % tpr;
        int tx = threadIdx.x & 31, ty = threadIdx.x >> 5;
        #pragma unroll
        for (int i = 0; i < 4; ++i)
            tile[ty + 8 * i][tx] = src[(size_t)(tr * 32 + ty + 8 * i) * n + tc * 32 + tx];
        __syncthreads();
        #pragma unroll
        for (int i = 0; i < 4; ++i)
            dst[(size_t)(tc * 32 + ty + 8 * i) * n + tr * 32 + tx] =
                __float2bfloat16(tile[tx][ty + 8 * i]);
        return;
    }
    const unsigned nE8 = (unsigned)num_seg * (EMBED / 8);
    const unsigned nD8 = (unsigned)num_seg * (DEC_EMBED / 8);
    const unsigned t0 = nE8;
    const unsigned t1 = t0 + nD8;
    const unsigned t2 = t1 + (unsigned)npts;                 // counts
    const unsigned n14 = (unsigned)npts * IN_CHANS / 4;      // out1 float4s
    const unsigned t3 = t2 + n14;
    const unsigned n24 = (unsigned)npts * 3 / 4;             // out2 float4s
    const unsigned t4 = t3 + n24;
    const unsigned nW4 = (unsigned)psize3 * (IN_CHANS * EMBED / 4); // W float4s
    const unsigned t5 = t4 + nW4;
    const unsigned stride = (unsigned)hcBlocks * blockDim.x;
    for (unsigned idx = blockIdx.x * blockDim.x + threadIdx.x; idx < t5; idx += stride) {
        if (idx < t0) {
            unsigned r = idx / (EMBED / 8), d = (idx % (EMBED / 8)) * 8;
            float c0 = coords[r * 3 + 0], c1 = coords[r * 3 + 1], c2 = coords[r * 3 + 2];
            float4 wa0 = *reinterpret_cast<const float4*>(w1e + 0 * EMBED + d);
            float4 wa1 = *reinterpret_cast<const float4*>(w1e + 0 * EMBED + d + 4);
            float4 wb0 = *reinterpret_cast<const float4*>(w1e + 1 * EMBED + d);
            float4 wb1 = *reinterpret_cast<const float4*>(w1e + 1 * EMBED + d + 4);
            float4 wc0 = *reinterpret_cast<const float4*>(w1e + 2 * EMBED + d);
            float4 wc1 = *reinterpret_cast<const float4*>(w1e + 2 * EMBED + d + 4);
            float4 bb0 = *reinterpret_cast<const float4*>(b1e + d);
            float4 bb1 = *reinterpret_cast<const float4*>(b1e + d + 4);
            union { short8 v; __hip_bfloat16 h[8]; } u;
            #pragma unroll
            for (int i = 0; i < 4; ++i)
                u.h[i] = __float2bfloat16(gelu_f(c0 * (&wa0.x)[i] + c1 * (&wb0.x)[i]
                                               + c2 * (&wc0.x)[i] + (&bb0.x)[i]));
            #pragma unroll
            for (int i = 0; i < 4; ++i)
                u.h[4 + i] = __float2bfloat16(gelu_f(c0 * (&wa1.x)[i] + c1 * (&wb1.x)[i]
                                                   + c2 * (&wc1.x)[i] + (&bb1.x)[i]));
            *reinterpret_cast<short8*>(&hE[(size_t)r * EMBED + d]) = u.v;
        } else if (idx < t1) {
            unsigned j = idx - t0;
            unsigned r = j / (DEC_EMBED / 8), d = (j % (DEC_EMBED / 8)) * 8;
            float c0 = coords[r * 3 + 0], c1 = coords[r * 3 + 1], c2 = coords[r * 3 + 2];
            float4 wa0 = *reinterpret_cast<const float4*>(w1d + 0 * DEC_EMBED + d);
            float4 wa1 = *reinterpret_cast<const float4*>(w1d + 0 * DEC_EMBED + d + 4);
            float4 wb0 = *reinterpret_cast<const float4*>(w1d + 1 * DEC_EMBED + d);
            float4 wb1 = *reinterpret_cast<const float4*>(w1d + 1 * DEC_EMBED + d + 4);
            float4 wc0 = *reinterpret_cast<const float4*>(w1d + 2 * DEC_EMBED + d);
            float4 wc1 = *reinterpret_cast<const float4*>(w1d + 2 * DEC_EMBED + d + 4);
            float4 bb0 = *reinterpret_cast<const float4*>(b1d + d);
            float4 bb1 = *reinterpret_cast<const float4*>(b1d + d + 4);
            union { short8 v; __hip_bfloat16 h[8]; } u;
            #pragma unroll
            for (int i = 0; i < 4; ++i)
                u.h[i] = __float2bfloat16(gelu_f(c0 * (&wa0.x)[i] + c1 * (&wb0.x)[i]
                                               + c2 * (&wc0.x)[i] + (&bb0.x)[i]));
            #pragma unroll
            for (int i = 0; i < 4; ++i)
                u.h[4 + i] = __float2bfloat16(gelu_f(c0 * (&wa1.x)[i] + c1 * (&wb1.x)[i]
                                                   + c2 * (&wc1.x)[i] + (&bb1.x)[i]));
            *reinterpret_cast<short8*>(&hD[(size_t)r * DEC_EMBED + d]) = u.v;
        } else if (idx < t2) {
            int i = (int)(idx - t1);
            atomicAdd(&qcount[q[i]], 1);
            atomicAdd(&segcnt[seg[i]], 1);
        } else if (idx < t3) {
            unsigned j = idx - t2;
            reinterpret_cast<float4*>(out1)[j] =
                reinterpret_cast<const float4*>(sel)[j];
        } else if (idx < t4) {
            unsigned j = idx - t3;
            reinterpret_cast<float4*>(out2)[j] =
                reinterpret_cast<const float4*>(selc)[j];
        } else {
            unsigned j = idx - t4;
            float4 v = reinterpret_cast<const float4*>(Wproj)[j];
            if (v.x != 1.0f || v.y != 1.0f || v.z != 1.0f || v.w != 1.0f)
                atomicOr(notones, 1);
        }
    }
}

// ---- both prefix sums in one launch (fallback only) ----

__global__ void prefix_both_kernel(const int* __restrict__ notones,
                                   const int* __restrict__ qcount, int* __restrict__ qoffs,
                                   int* __restrict__ qfill, int psize3,
                                   const int* __restrict__ segcnt, int* __restrict__ seg_offs,
                                   int* __restrict__ segfill, int num_seg) {
    if (*notones == 0) return;
    const int* cnt; int* offs; int* fill; int n;
    if (blockIdx.x == 0) { cnt = qcount; offs = qoffs;    fill = qfill;   n = psize3; }
    else                 { cnt = segcnt; offs = seg_offs; fill = segfill; n = num_seg; }
    __shared__ int partial[NTHREADS];
    int t = threadIdx.x;
    int per = (n + NTHREADS - 1) / NTHREADS;
    int s = 0;
    for (int i = 0; i < per; ++i) {
        int idx = t * per + i;
        if (idx < n) s += cnt[idx];
    }
    partial[t] = s;
    __syncthreads();
    if (t == 0) {
        int run = 0;
        for (int i = 0; i < NTHREADS; ++i) { int v = partial[i]; partial[i] = run; run += v; }
    }
    __syncthreads();
    int run = partial[t];
    for (int i = 0; i < per; ++i) {
        int idx = t * per + i;
        if (idx < n) {
            offs[idx] = run;
            fill[idx] = run;
            run += cnt[idx];
        }
    }
    if (t == NTHREADS - 1) offs[n] = run;
}

// ---- fill: bucket-order records {sel[6]} + perm (fallback only) ----

__global__ void fill_kernel(const int* __restrict__ notones,
                            const int* __restrict__ q, const int* __restrict__ seg,
                            const float* __restrict__ sel,
                            int* __restrict__ qfill, int* __restrict__ segfill,
                            int* __restrict__ bucket, float* __restrict__ rec,
                            int* __restrict__ perm, int npts) {
    if (*notones == 0) return;
    int i = blockIdx.x * blockDim.x + threadIdx.x;
    if (i < npts) {
        int pos = atomicAdd(&qfill[q[i]], 1);
        bucket[pos] = i;
        int sp = atomicAdd(&segfill[seg[i]], 1);
        if (rec) {
            perm[sp] = pos;
            const float2* s2 = reinterpret_cast<const float2*>(sel + (size_t)i * IN_CHANS);
            float2 a = s2[0], b = s2[1], c = s2[2];
            float4* rp = reinterpret_cast<float4*>(rec) + (size_t)pos * 2;
            rp[0] = make_float4(a.x, a.y, b.x, b.y);
            rp[1] = make_float4(c.x, c.y, 0.f, 0.f);
        }
    }
}

// ---- FAST PATH (W==1): per-point row-sum -> per-segment atomic sum ----

__global__ void fastsum_kernel(const int* __restrict__ notones,
                               const float* __restrict__ sel, const int* __restrict__ seg,
                               float* __restrict__ segsum, int npts) {
    if (*notones != 0) return;
    int i = blockIdx.x * blockDim.x + threadIdx.x;
    if (i < npts) {
        const float2* s2 = reinterpret_cast<const float2*>(sel + (size_t)i * IN_CHANS);
        float2 a = s2[0], b = s2[1], c = s2[2];
        float s = a.x + a.y + b.x + b.y + c.x + c.y;
        unsafeAtomicAdd(&segsum[seg[i]], s);
    }
}

// ---- FAST PATH: broadcast mean to out0 rows ----

__global__ void broadcast_kernel(const int* __restrict__ notones,
                                 const float* __restrict__ segsum,
                                 const int* __restrict__ segcnt,
                                 const int* __restrict__ pad_idx,
                                 float* __restrict__ out0, int num_seg) {
    if (*notones != 0) return;
    int total = num_seg * (EMBED / 4);
    for (int idx = blockIdx.x * blockDim.x + threadIdx.x; idx < total;
         idx += gridDim.x * blockDim.x) {
        int s = idx / (EMBED / 4), d4 = idx % (EMBED / 4);
        float val = segsum[s] / (float)max(segcnt[s], 1);
        float4 v = make_float4(val, val, val, val);
        *reinterpret_cast<float4*>(&out0[(size_t)pad_idx[s] * EMBED + 4 * d4]) = v;
    }
}

// ---- projection -> bf16 feats in BUCKET order (fallback only) ----

__global__ __launch_bounds__(384, 6)
void project_store_kernel(const int* __restrict__ notones,
                          const float* __restrict__ W,
                          const float* __restrict__ rec,
                          const int* __restrict__ qoffs,
                          __hip_bfloat16* __restrict__ feats, int psize3) {
    if (*notones == 0) return;
    int qi = blockIdx.x;
    int t = threadIdx.x;          // 0..383
    int g  = t / 96;              // point-parity group 0..3
    int d8 = (t % 96) * 8;        // owned dims [d8, d8+8)
    const float* Wg = W + (size_t)qi * IN_CHANS * EMBED + d8;
    float4 wA[IN_CHANS], wB[IN_CHANS];
    #pragma unroll
    for (int c = 0; c < IN_CHANS; ++c) {
        wA[c] = *reinterpret_cast<const float4*>(Wg + c * EMBED);
        wB[c] = *reinterpret_cast<const float4*>(Wg + c * EMBED + 4);
    }

    __shared__ float4 buf[128];
    const float4* rp = reinterpret_cast<const float4*>(rec);
    int beg = qoffs[qi], end = qoffs[qi + 1];
    for (int base = beg; base < end; base += 64) {
        int chunk = min(64, end - base);
        __syncthreads();
        if (t < chunk * 2) buf[t] = rp[(size_t)base * 2 + t];
        __syncthreads();
        for (int pp = 0; pp < chunk; pp += 4) {
            int p = pp + g;
            if (p < chunk) {
                float4 ra = buf[2 * p];
                float4 rb = buf[2 * p + 1];
                union { short8 v; __hip_bfloat16 h[8]; } u;
                #pragma unroll
                for (int i = 0; i < 4; ++i) {
                    float f = ra.x * (&wA[0].x)[i] + ra.y * (&wA[1].x)[i]
                            + ra.z * (&wA[2].x)[i] + ra.w * (&wA[3].x)[i]
                            + rb.x * (&wA[4].x)[i] + rb.y * (&wA[5].x)[i];
                    u.h[i] = __float2bfloat16(f);
                }
                #pragma unroll
                for (int i = 0; i < 4; ++i) {
                    float f = ra.x * (&wB[0].x)[i] + ra.y * (&wB[1].x)[i]
                            + ra.z * (&wB[2].x)[i] + ra.w * (&wB[3].x)[i]
                            + rb.x * (&wB[4].x)[i] + rb.y * (&wB[5].x)[i];
                    u.h[4 + i] = __float2bfloat16(f);
                }
                *reinterpret_cast<short8*>(&feats[(size_t)(base + p) * EMBED + d8]) = u.v;
            }
        }
    }
}

// ---- seg gather-mean via perm (fallback only) ----

__global__ void seg_reduce_kernel(const int* __restrict__ notones,
                                  const __hip_bfloat16* __restrict__ feats,
                                  const int* __restrict__ seg_offs,
                                  const int* __restrict__ perm,
                                  const int* __restrict__ pad_idx,
                                  float* __restrict__ out0) {
    if (*notones == 0) return;
    int s = blockIdx.x;
    int t = threadIdx.x;          // 0..191
    int g  = t / 96;
    int ts = t % 96;
    int d8 = ts * 8;
    int beg = seg_offs[s], end = seg_offs[s + 1];
    int cnt = end - beg;
    __shared__ int rows[256];
    __shared__ float comb[96 * 8];
    for (int j = t; j < cnt; j += 192) rows[j] = perm[beg + j];
    __syncthreads();
    float a[8];
    #pragma unroll
    for (int i = 0; i < 8; ++i) a[i] = 0.f;
    for (int i = g; i < cnt; i += 2) {
        uint4_t v = *reinterpret_cast<const uint4_t*>(&feats[(size_t)rows[i] * EMBED + d8]);
        a[0] += __uint_as_float(v.x << 16);
        a[1] += __uint_as_float(v.x & 0xffff0000u);
        a[2] += __uint_as_float(v.y << 16);
        a[3] += __uint_as_float(v.y & 0xffff0000u);
        a[4] += __uint_as_float(v.z << 16);
        a[5] += __uint_as_float(v.z & 0xffff0000u);
        a[6] += __uint_as_float(v.w << 16);
        a[7] += __uint_as_float(v.w & 0xffff0000u);
    }
    if (g == 1) {
        #pragma unroll
        for (int i = 0; i < 8; ++i) comb[ts * 8 + i] = a[i];
    }
    __syncthreads();
    if (g == 0) {
        float inv = 1.0f / (float)max(cnt, 1);
        size_t j = (size_t)pad_idx[s];
        float4 o0, o1;
        #pragma unroll
        for (int i = 0; i < 4; ++i) (&o0.x)[i] = (a[i] + comb[ts * 8 + i]) * inv;
        #pragma unroll
        for (int i = 0; i < 4; ++i) (&o1.x)[i] = (a[4 + i] + comb[ts * 8 + 4 + i]) * inv;
        *reinterpret_cast<float4*>(&out0[j * EMBED + d8]) = o0;
        *reinterpret_cast<float4*>(&out0[j * EMBED + d8 + 4]) = o1;
    }
}

// ---- fallback path (small ws): atomic scatter ----

__global__ void project_kernel(const int* __restrict__ notones,
                               const float* __restrict__ sel, const int* __restrict__ seg,
                               const int* __restrict__ pad_idx, const float* __restrict__ W,
                               const int* __restrict__ bucket, const int* __restrict__ qoffs,
                               float* __restrict__ out0) {
    if (*notones == 0) return;
    int qi = blockIdx.x;
    __shared__ float Wl[IN_CHANS * EMBED];
    __shared__ float sel_l[64][IN_CHANS];
    __shared__ int   j_l[64];
    int t = threadIdx.x;
    const float* Wg = W + (size_t)qi * IN_CHANS * EMBED;
    for (int i = t; i < IN_CHANS * EMBED; i += NTHREADS) Wl[i] = Wg[i];
    int beg = qoffs[qi], end = qoffs[qi + 1];
    __syncthreads();
    for (int base = beg; base < end; base += 64) {
        int chunk = min(64, end - base);
        if (t < chunk) {
            int n = bucket[base + t];
            #pragma unroll
            for (int c = 0; c < IN_CHANS; ++c) sel_l[t][c] = sel[(size_t)n * IN_CHANS + c];
            j_l[t] = pad_idx[seg[n]];
        }
        __syncthreads();
        for (int p = 0; p < chunk; ++p) {
            float s0 = sel_l[p][0], s1 = sel_l[p][1], s2 = sel_l[p][2];
            float s3 = sel_l[p][3], s4 = sel_l[p][4], s5 = sel_l[p][5];
            size_t j = (size_t)j_l[p];
            #pragma unroll
            for (int r = 0; r < 3; ++r) {
                int d = r * NTHREADS + t;
                float f = s0 * Wl[0 * EMBED + d] + s1 * Wl[1 * EMBED + d]
                        + s2 * Wl[2 * EMBED + d] + s3 * Wl[3 * EMBED + d]
                        + s4 * Wl[4 * EMBED + d] + s5 * Wl[5 * EMBED + d];
                unsafeAtomicAdd(&out0[j * EMBED + d], f);
            }
        }
        __syncthreads();
    }
}

__global__ void finalize_kernel(const int* __restrict__ notones,
                                const int* __restrict__ segcnt, const int* __restrict__ pad_idx,
                                float* __restrict__ out0, int num_seg) {
    if (*notones == 0) return;
    int total = num_seg * EMBED;
    for (int idx = blockIdx.x * blockDim.x + threadIdx.x; idx < total;
         idx += gridDim.x * blockDim.x) {
        int i = idx / EMBED, d = idx % EMBED;
        int c = segcnt[i];
        float inv = 1.0f / (float)max(c, 1);
        out0[(size_t)pad_idx[i] * EMBED + d] *= inv;
    }
}

// ---- bf16 MFMA GEMM via LDS (m97 structure): out (+)= h @ w2 + b2 ----

__global__ __launch_bounds__(256, 4)
void gemm_lds_kernel(const __hip_bfloat16* __restrict__ hE,
                     const __hip_bfloat16* __restrict__ w2tE,
                     const float* __restrict__ b2e,
                     const __hip_bfloat16* __restrict__ hD,
                     const __hip_bfloat16* __restrict__ w2tD,
                     const float* __restrict__ b2d,
                     float* __restrict__ out0, float* __restrict__ out3,
                     int M, int nblkE) {
    int nblk = gridDim.x;
    int bid = blockIdx.x;
    int q8 = nblk >> 3, r8 = nblk & 7;
    int xcd = bid & 7, idx = bid >> 3;
    int bx = (xcd < r8 ? xcd * (q8 + 1) : r8 * (q8 + 1) + (xcd - r8) * q8) + idx;

    const short* A;
    const short* Bt;
    const float* b2;
    float* out;
    int N, K;
    bool accum;
    if (bx < nblkE) {
        A = (const short*)hE; Bt = (const short*)w2tE; b2 = b2e; out = out0;
        N = EMBED; K = EMBED; accum = true;
    } else {
        bx -= nblkE;
        A = (const short*)hD; Bt = (const short*)w2tD; b2 = b2d; out = out3;
        N = DEC_EMBED; K = DEC_EMBED; accum = false;
    }
    constexpr int BM = 128, BN = 64, BK = 32;
    int ctiles = N / BN;
    int rt = bx / ctiles, ct = bx % ctiles;

    __shared__ short Al[BM * BK];
    __shared__ short Bl[BN * BK];

    int t = threadIdx.x;
    int lane = t & 63;
    int w = t >> 6;
    int wr = w >> 1, wc = w & 1;
    int r0 = wr * 64;
    int c0 = wc * 32;

    int lrow = lane & 15;
    int kgrp = (lane >> 4) << 3;

    int oA = t * 16;
    int rowA0 = oA >> 6;
    int kkA  = (oA & 63) >> 1;
    int rowA1 = rowA0 + 64;
    int rowB = oA >> 6;

    int gA0 = rt * BM + rowA0; if (gA0 >= M) gA0 = M - 1;
    int gA1 = rt * BM + rowA1; if (gA1 >= M) gA1 = M - 1;
    const short* a0p = A + (size_t)gA0 * K + kkA;
    const short* a1p = A + (size_t)gA1 * K + kkA;
    const short* bp  = Bt + (size_t)(ct * BN + rowB) * K + kkA;
    short* la0 = &Al[t * 8];
    short* la1 = &Al[t * 8 + 2048];
    short* lb  = &Bl[t * 8];

    f32x4 acc[4][2];
    #pragma unroll
    for (int mi = 0; mi < 4; ++mi)
        #pragma unroll
        for (int ni = 0; ni < 2; ++ni) acc[mi][ni] = f32x4{0.f, 0.f, 0.f, 0.f};

    for (int k0 = 0; k0 < K; k0 += BK) {
        gload_lds16(a0p + k0, la0);
        gload_lds16(a1p + k0, la1);
        gload_lds16(bp + k0, lb);
        __syncthreads();
        short8 af[4], bf[2];
        #pragma unroll
        for (int mi = 0; mi < 4; ++mi)
            af[mi] = *reinterpret_cast<const short8*>(&Al[(r0 + mi * 16 + lrow) * BK + kgrp]);
        #pragma unroll
        for (int ni = 0; ni < 2; ++ni)
            bf[ni] = *reinterpret_cast<const short8*>(&Bl[(c0 + ni * 16 + lrow) * BK + kgrp]);
        #pragma unroll
        for (int mi = 0; mi < 4; ++mi)
            #pragma unroll
            for (int ni = 0; ni < 2; ++ni)
                acc[mi][ni] = __builtin_amdgcn_mfma_f32_16x16x32_bf16(af[mi], bf[ni],
                                                                      acc[mi][ni], 0, 0, 0);
        __syncthreads();
    }

    int rbase = (lane >> 4) << 2;
    #pragma unroll
    for (int ni = 0; ni < 2; ++ni) {
        int col = ct * BN + c0 + ni * 16 + lrow;
        float bb = b2[col];
        #pragma unroll
        for (int mi = 0; mi < 4; ++mi) {
            #pragma unroll
            for (int j = 0; j < 4; ++j) {
                int row = rt * BM + r0 + mi * 16 + rbase + j;
                if (row < M) {
                    size_t o = (size_t)row * N + col;
                    float v = acc[mi][ni][j] + bb;
                    if (accum) out[o] += v;
                    else       out[o]  = v;
                }
            }
        }
    }
}

// ---------------- host ----------------

extern "C" void kernel_launch(void* const* d_in, const int* in_sizes, int n_in,
                              void* d_out, int out_size, void* d_ws, size_t ws_size,
                              hipStream_t stream) {
    const float* sel_features = (const float*)d_in[0];
    const int*   q            = (const int*)d_in[1];
    const int*   seg          = (const int*)d_in[2];
    const int*   pad_idx      = (const int*)d_in[3];
    const float* coords       = (const float*)d_in[4];
    const float* sel_coors    = (const float*)d_in[5];
    const float* W            = (const float*)d_in[7];
    const float* w1e          = (const float*)d_in[8];
    const float* b1e          = (const float*)d_in[9];
    const float* w2e          = (const float*)d_in[10];
    const float* b2e          = (const float*)d_in[11];
    const float* w1d          = (const float*)d_in[12];
    const float* b1d          = (const float*)d_in[13];
    const float* w2d          = (const float*)d_in[14];
    const float* b2d          = (const float*)d_in[15];

    int npts    = in_sizes[1];
    int num_seg = in_sizes[3];
    int psize3  = in_sizes[7] / (IN_CHANS * EMBED);

    float* out  = (float*)d_out;
    float* out0 = out;                                       // [num_seg, 768]
    float* out1 = out0 + (size_t)num_seg * EMBED;            // sel_features copy
    float* out2 = out1 + (size_t)npts * IN_CHANS;            // sel_coors copy
    float* out3 = out2 + (size_t)npts * 3;                   // [num_seg, 512]

    // ws layout (big): feats | hE hD w2tE w2tD | rec | ints
    size_t feats_elems = (size_t)npts * EMBED;
    size_t mlp_elems = (size_t)num_seg * EMBED + (size_t)num_seg * DEC_EMBED
                     + (size_t)EMBED * EMBED + (size_t)DEC_EMBED * DEC_EMBED;
    size_t rec_bytes = (size_t)npts * 32;
    size_t n_ints = (size_t)psize3 * 2 + 1 + (size_t)num_seg * 3 + 1
                  + (size_t)npts * 2 + 32;
    size_t need_big = (feats_elems + mlp_elems) * 2 + rec_bytes + n_ints * 4;
    bool big = ws_size >= need_big;

    char* wsb = (char*)d_ws;
    __hip_bfloat16* feats = (__hip_bfloat16*)wsb;
    __hip_bfloat16* hE   = big ? feats + feats_elems : (__hip_bfloat16*)wsb;
    __hip_bfloat16* hD   = hE + (size_t)num_seg * EMBED;
    __hip_bfloat16* w2tE = hD + (size_t)num_seg * DEC_EMBED;
    __hip_bfloat16* w2tD = w2tE + (size_t)EMBED * EMBED;
    float* rec   = big ? (float*)(w2tD + (size_t)DEC_EMBED * DEC_EMBED) : nullptr;
    int* wsi     = big ? (int*)((char*)rec + rec_bytes)
                       : (int*)(w2tD + (size_t)DEC_EMBED * DEC_EMBED);
    // zeroed region: qcount | segcnt | segsum | notones
    int*   qcount  = wsi;                         // psize3
    int*   segcnt  = qcount + psize3;             // num_seg
    float* segsum  = (float*)(segcnt + num_seg);  // num_seg (0.0f == all-zero bits)
    int*   notones = (int*)(segsum + num_seg);    // 1
    int*   qoffs   = notones + 1;                 // psize3+1
    int*   qfill   = qoffs + psize3 + 1;          // psize3
    int*   seg_offs= qfill + psize3;              // num_seg+1
    int*   segfill = seg_offs + num_seg + 1;      // num_seg
    int*   bucket  = segfill + num_seg;           // npts
    int*   perm    = bucket + npts;               // npts

    hipMemsetAsync(qcount, 0, sizeof(int) * (size_t)(psize3 + 2 * num_seg + 1), stream);

    int hcBlocks = 2048;
    int ntE = (EMBED / 32) * (EMBED / 32);
    int ntD = (DEC_EMBED / 32) * (DEC_EMBED / 32);
    hc_kernel<<<hcBlocks + ntE + ntD, NTHREADS, 0, stream>>>(
        coords, w1e, b1e, w1d, b1d, q, seg, sel_features, sel_coors,
        w2e, w2d, W, hE, hD, w2tE, w2tD, qcount, segcnt, notones, out1, out2,
        hcBlocks, num_seg, npts, psize3);
    prefix_both_kernel<<<2, NTHREADS, 0, stream>>>(notones, qcount, qoffs, qfill, psize3,
                                                   segcnt, seg_offs, segfill, num_seg);
    int pb = (npts + NTHREADS - 1) / NTHREADS;
    fill_kernel<<<pb, NTHREADS, 0, stream>>>(notones, q, seg, sel_features, qfill, segfill,
                                             bucket, rec, perm, npts);
    fastsum_kernel<<<pb, NTHREADS, 0, stream>>>(notones, sel_features, seg, segsum, npts);

    if (big) {
        project_store_kernel<<<psize3, 384, 0, stream>>>(notones, W, rec, qoffs, feats,
                                                         psize3);
        seg_reduce_kernel<<<num_seg, 192, 0, stream>>>(notones, feats, seg_offs, perm,
                                                       pad_idx, out0);
    } else {
        project_kernel<<<psize3, NTHREADS, 0, stream>>>(notones, sel_features, seg, pad_idx,
                                                        W, bucket, qoffs, out0);
        finalize_kernel<<<2048, NTHREADS, 0, stream>>>(notones, segcnt, pad_idx, out0,
                                                       num_seg);
    }
    int bb = (num_seg * (EMBED / 4) + NTHREADS - 1) / NTHREADS;
    broadcast_kernel<<<min(bb, 4704), NTHREADS, 0, stream>>>(notones, segsum, segcnt,
                                                             pad_idx, out0, num_seg);

    int rtiles = (num_seg + 127) / 128;
    int nblkE = rtiles * (EMBED / 64);
    int nblkD = rtiles * (DEC_EMBED / 64);
    gemm_lds_kernel<<<nblkE + nblkD, NTHREADS, 0, stream>>>(hE, w2tE, b2e, hD, w2tD, b2d,
                                                            out0, out3, num_seg, nblkE);
}

// Round 17
// 81.376 us; speedup vs baseline: 2.3837x; 1.2602x over previous
//
#include <hip/hip_runtime.h>
#include <hip/hip_bf16.h>
#include <cmath>

#define NTHREADS 256

constexpr int IN_CHANS = 6;
constexpr int EMBED = 768;
constexpr int DEC_EMBED = 512;

typedef __attribute__((ext_vector_type(8))) short short8;
typedef __attribute__((ext_vector_type(4))) float f32x4;

__device__ __forceinline__ void gload_lds16(const short* g, short* l) {
    __builtin_amdgcn_global_load_lds((const __attribute__((address_space(1))) void*)g,
                                     (__attribute__((address_space(3))) void*)l, 16, 0, 0);
}

__device__ __forceinline__ float gelu_f(float x) {
    return 0.5f * x * (1.0f + erff(x * 0.70710678118654752f));
}

// ---- fused hc: 3 block roles ----
// [0, hcBlocks):            gelu h, segcnt+segsum (fastsum), out1/out2 copies
// [hcBlocks, +ckBlocks):    W==1 streaming check (4x float4 per iteration)
// [hcBlocks+ckBlocks, ...): w2 transpose tiles

__global__ void hc_kernel(const float* __restrict__ coords,
                          const float* __restrict__ w1e, const float* __restrict__ b1e,
                          const float* __restrict__ w1d, const float* __restrict__ b1d,
                          const int* __restrict__ seg,
                          const float* __restrict__ sel, const float* __restrict__ selc,
                          const float* __restrict__ w2e, const float* __restrict__ w2d,
                          const float* __restrict__ Wproj,
                          __hip_bfloat16* __restrict__ hE, __hip_bfloat16* __restrict__ hD,
                          __hip_bfloat16* __restrict__ w2tE, __hip_bfloat16* __restrict__ w2tD,
                          int* __restrict__ segcnt, float* __restrict__ segsum,
                          int* __restrict__ notones,
                          float* __restrict__ out1, float* __restrict__ out2,
                          int hcBlocks, int ckBlocks, int num_seg, int npts, int psize3) {
    __shared__ float tile[32][33];
    int bid = blockIdx.x;
    if (bid >= hcBlocks + ckBlocks) {
        // ---- transpose role ----
        int b = bid - hcBlocks - ckBlocks;
        const float* src; __hip_bfloat16* dst; int n;
        const int ntE = (EMBED / 32) * (EMBED / 32);
        if (b < ntE) { src = w2e; dst = w2tE; n = EMBED; }
        else         { b -= ntE; src = w2d; dst = w2tD; n = DEC_EMBED; }
        int tpr = n / 32;
        int tr = b / tpr, tc = b % tpr;
        int tx = threadIdx.x & 31, ty = threadIdx.x >> 5;
        #pragma unroll
        for (int i = 0; i < 4; ++i)
            tile[ty + 8 * i][tx] = src[(size_t)(tr * 32 + ty + 8 * i) * n + tc * 32 + tx];
        __syncthreads();
        #pragma unroll
        for (int i = 0; i < 4; ++i)
            dst[(size_t)(tc * 32 + ty + 8 * i) * n + tr * 32 + tx] =
                __float2bfloat16(tile[tx][ty + 8 * i]);
        return;
    }
    if (bid >= hcBlocks) {
        // ---- W-check role: tight streaming, 4 loads in flight ----
        int b = bid - hcBlocks;
        const unsigned total4 = (unsigned)psize3 * (IN_CHANS * EMBED / 4);
        const unsigned stride4 = (unsigned)ckBlocks * blockDim.x * 4u;
        const float4* p = reinterpret_cast<const float4*>(Wproj);
        bool bad = false;
        for (unsigned i = ((unsigned)b * blockDim.x + threadIdx.x) * 4u; i < total4;
             i += stride4) {
            float4 v0 = p[i], v1 = p[i + 1], v2 = p[i + 2], v3 = p[i + 3];
            bad |= v0.x != 1.f || v0.y != 1.f || v0.z != 1.f || v0.w != 1.f;
            bad |= v1.x != 1.f || v1.y != 1.f || v1.z != 1.f || v1.w != 1.f;
            bad |= v2.x != 1.f || v2.y != 1.f || v2.z != 1.f || v2.w != 1.f;
            bad |= v3.x != 1.f || v3.y != 1.f || v3.z != 1.f || v3.w != 1.f;
        }
        if (bad) atomicOr(notones, 1);
        return;
    }
    // ---- main role ----
    const unsigned nE8 = (unsigned)num_seg * (EMBED / 8);
    const unsigned nD8 = (unsigned)num_seg * (DEC_EMBED / 8);
    const unsigned t0 = nE8;
    const unsigned t1 = t0 + nD8;
    const unsigned t2 = t1 + (unsigned)npts;                 // counts + rowsum
    const unsigned n14 = (unsigned)npts * IN_CHANS / 4;      // out1 float4s
    const unsigned t3 = t2 + n14;
    const unsigned n24 = (unsigned)npts * 3 / 4;             // out2 float4s
    const unsigned t4 = t3 + n24;
    const unsigned stride = (unsigned)hcBlocks * blockDim.x;
    for (unsigned idx = bid * blockDim.x + threadIdx.x; idx < t4; idx += stride) {
        if (idx < t0) {
            unsigned r = idx / (EMBED / 8), d = (idx % (EMBED / 8)) * 8;
            float c0 = coords[r * 3 + 0], c1 = coords[r * 3 + 1], c2 = coords[r * 3 + 2];
            float4 wa0 = *reinterpret_cast<const float4*>(w1e + 0 * EMBED + d);
            float4 wa1 = *reinterpret_cast<const float4*>(w1e + 0 * EMBED + d + 4);
            float4 wb0 = *reinterpret_cast<const float4*>(w1e + 1 * EMBED + d);
            float4 wb1 = *reinterpret_cast<const float4*>(w1e + 1 * EMBED + d + 4);
            float4 wc0 = *reinterpret_cast<const float4*>(w1e + 2 * EMBED + d);
            float4 wc1 = *reinterpret_cast<const float4*>(w1e + 2 * EMBED + d + 4);
            float4 bb0 = *reinterpret_cast<const float4*>(b1e + d);
            float4 bb1 = *reinterpret_cast<const float4*>(b1e + d + 4);
            union { short8 v; __hip_bfloat16 h[8]; } u;
            #pragma unroll
            for (int i = 0; i < 4; ++i)
                u.h[i] = __float2bfloat16(gelu_f(c0 * (&wa0.x)[i] + c1 * (&wb0.x)[i]
                                               + c2 * (&wc0.x)[i] + (&bb0.x)[i]));
            #pragma unroll
            for (int i = 0; i < 4; ++i)
                u.h[4 + i] = __float2bfloat16(gelu_f(c0 * (&wa1.x)[i] + c1 * (&wb1.x)[i]
                                                   + c2 * (&wc1.x)[i] + (&bb1.x)[i]));
            *reinterpret_cast<short8*>(&hE[(size_t)r * EMBED + d]) = u.v;
        } else if (idx < t1) {
            unsigned j = idx - t0;
            unsigned r = j / (DEC_EMBED / 8), d = (j % (DEC_EMBED / 8)) * 8;
            float c0 = coords[r * 3 + 0], c1 = coords[r * 3 + 1], c2 = coords[r * 3 + 2];
            float4 wa0 = *reinterpret_cast<const float4*>(w1d + 0 * DEC_EMBED + d);
            float4 wa1 = *reinterpret_cast<const float4*>(w1d + 0 * DEC_EMBED + d + 4);
            float4 wb0 = *reinterpret_cast<const float4*>(w1d + 1 * DEC_EMBED + d);
            float4 wb1 = *reinterpret_cast<const float4*>(w1d + 1 * DEC_EMBED + d + 4);
            float4 wc0 = *reinterpret_cast<const float4*>(w1d + 2 * DEC_EMBED + d);
            float4 wc1 = *reinterpret_cast<const float4*>(w1d + 2 * DEC_EMBED + d + 4);
            float4 bb0 = *reinterpret_cast<const float4*>(b1d + d);
            float4 bb1 = *reinterpret_cast<const float4*>(b1d + d + 4);
            union { short8 v; __hip_bfloat16 h[8]; } u;
            #pragma unroll
            for (int i = 0; i < 4; ++i)
                u.h[i] = __float2bfloat16(gelu_f(c0 * (&wa0.x)[i] + c1 * (&wb0.x)[i]
                                               + c2 * (&wc0.x)[i] + (&bb0.x)[i]));
            #pragma unroll
            for (int i = 0; i < 4; ++i)
                u.h[4 + i] = __float2bfloat16(gelu_f(c0 * (&wa1.x)[i] + c1 * (&wb1.x)[i]
                                                   + c2 * (&wc1.x)[i] + (&bb1.x)[i]));
            *reinterpret_cast<short8*>(&hD[(size_t)r * DEC_EMBED + d]) = u.v;
        } else if (idx < t2) {
            int i = (int)(idx - t1);
            int s = seg[i];
            atomicAdd(&segcnt[s], 1);
            const float2* s2 = reinterpret_cast<const float2*>(sel + (size_t)i * IN_CHANS);
            float2 a = s2[0], b = s2[1], c = s2[2];
            unsafeAtomicAdd(&segsum[s], a.x + a.y + b.x + b.y + c.x + c.y);
        } else if (idx < t3) {
            unsigned j = idx - t2;
            reinterpret_cast<float4*>(out1)[j] =
                reinterpret_cast<const float4*>(sel)[j];
        } else {
            unsigned j = idx - t3;
            reinterpret_cast<float4*>(out2)[j] =
                reinterpret_cast<const float4*>(selc)[j];
        }
    }
}

// ---- broadcast: fast path writes segment means; fallback zero-fills out0 ----

__global__ void broadcast_kernel(const int* __restrict__ notones,
                                 const float* __restrict__ segsum,
                                 const int* __restrict__ segcnt,
                                 const int* __restrict__ pad_idx,
                                 float* __restrict__ out0, int num_seg) {
    bool fb = (*notones != 0);
    int total = num_seg * (EMBED / 4);
    for (int idx = blockIdx.x * blockDim.x + threadIdx.x; idx < total;
         idx += gridDim.x * blockDim.x) {
        int s = idx / (EMBED / 4), d4 = idx % (EMBED / 4);
        float val = fb ? 0.f : segsum[s] / (float)max(segcnt[s], 1);
        float4 v = make_float4(val, val, val, val);
        *reinterpret_cast<float4*>(&out0[(size_t)pad_idx[s] * EMBED + 4 * d4]) = v;
    }
}

// ---- fallback (W != 1, never expected): direct atomic scatter, pre-scaled ----

__global__ void fallback_project_kernel(const int* __restrict__ notones,
                                        const float* __restrict__ sel,
                                        const int* __restrict__ q,
                                        const int* __restrict__ seg,
                                        const int* __restrict__ segcnt,
                                        const int* __restrict__ pad_idx,
                                        const float* __restrict__ W,
                                        float* __restrict__ out0, int npts) {
    if (*notones == 0) return;
    long total = (long)npts * (EMBED / 4);
    for (long idx = blockIdx.x * (long)blockDim.x + threadIdx.x; idx < total;
         idx += (long)gridDim.x * blockDim.x) {
        int n = (int)(idx / (EMBED / 4));
        int d4 = (int)(idx % (EMBED / 4)) * 4;
        int s = seg[n];
        float inv = 1.0f / (float)max(segcnt[s], 1);
        const float* Wr = W + (size_t)q[n] * IN_CHANS * EMBED + d4;
        float acc[4] = {0.f, 0.f, 0.f, 0.f};
        #pragma unroll
        for (int c = 0; c < IN_CHANS; ++c) {
            float sv = sel[(size_t)n * IN_CHANS + c];
            float4 wv = *reinterpret_cast<const float4*>(Wr + c * EMBED);
            acc[0] += sv * wv.x; acc[1] += sv * wv.y;
            acc[2] += sv * wv.z; acc[3] += sv * wv.w;
        }
        size_t j = (size_t)pad_idx[s];
        #pragma unroll
        for (int i = 0; i < 4; ++i)
            unsafeAtomicAdd(&out0[j * EMBED + d4 + i], acc[i] * inv);
    }
}

// ---- bf16 MFMA GEMM via LDS (m97 structure): out (+)= h @ w2 + b2 ----

__global__ __launch_bounds__(256, 4)
void gemm_lds_kernel(const __hip_bfloat16* __restrict__ hE,
                     const __hip_bfloat16* __restrict__ w2tE,
                     const float* __restrict__ b2e,
                     const __hip_bfloat16* __restrict__ hD,
                     const __hip_bfloat16* __restrict__ w2tD,
                     const float* __restrict__ b2d,
                     float* __restrict__ out0, float* __restrict__ out3,
                     int M, int nblkE) {
    int nblk = gridDim.x;
    int bid = blockIdx.x;
    int q8 = nblk >> 3, r8 = nblk & 7;
    int xcd = bid & 7, idx = bid >> 3;
    int bx = (xcd < r8 ? xcd * (q8 + 1) : r8 * (q8 + 1) + (xcd - r8) * q8) + idx;

    const short* A;
    const short* Bt;
    const float* b2;
    float* out;
    int N, K;
    bool accum;
    if (bx < nblkE) {
        A = (const short*)hE; Bt = (const short*)w2tE; b2 = b2e; out = out0;
        N = EMBED; K = EMBED; accum = true;
    } else {
        bx -= nblkE;
        A = (const short*)hD; Bt = (const short*)w2tD; b2 = b2d; out = out3;
        N = DEC_EMBED; K = DEC_EMBED; accum = false;
    }
    constexpr int BM = 128, BN = 64, BK = 32;
    int ctiles = N / BN;
    int rt = bx / ctiles, ct = bx % ctiles;

    __shared__ short Al[BM * BK];
    __shared__ short Bl[BN * BK];

    int t = threadIdx.x;
    int lane = t & 63;
    int w = t >> 6;
    int wr = w >> 1, wc = w & 1;
    int r0 = wr * 64;
    int c0 = wc * 32;

    int lrow = lane & 15;
    int kgrp = (lane >> 4) << 3;

    int oA = t * 16;
    int rowA0 = oA >> 6;
    int kkA  = (oA & 63) >> 1;
    int rowA1 = rowA0 + 64;
    int rowB = oA >> 6;

    int gA0 = rt * BM + rowA0; if (gA0 >= M) gA0 = M - 1;
    int gA1 = rt * BM + rowA1; if (gA1 >= M) gA1 = M - 1;
    const short* a0p = A + (size_t)gA0 * K + kkA;
    const short* a1p = A + (size_t)gA1 * K + kkA;
    const short* bp  = Bt + (size_t)(ct * BN + rowB) * K + kkA;
    short* la0 = &Al[t * 8];
    short* la1 = &Al[t * 8 + 2048];
    short* lb  = &Bl[t * 8];

    f32x4 acc[4][2];
    #pragma unroll
    for (int mi = 0; mi < 4; ++mi)
        #pragma unroll
        for (int ni = 0; ni < 2; ++ni) acc[mi][ni] = f32x4{0.f, 0.f, 0.f, 0.f};

    for (int k0 = 0; k0 < K; k0 += BK) {
        gload_lds16(a0p + k0, la0);
        gload_lds16(a1p + k0, la1);
        gload_lds16(bp + k0, lb);
        __syncthreads();
        short8 af[4], bf[2];
        #pragma unroll
        for (int mi = 0; mi < 4; ++mi)
            af[mi] = *reinterpret_cast<const short8*>(&Al[(r0 + mi * 16 + lrow) * BK + kgrp]);
        #pragma unroll
        for (int ni = 0; ni < 2; ++ni)
            bf[ni] = *reinterpret_cast<const short8*>(&Bl[(c0 + ni * 16 + lrow) * BK + kgrp]);
        #pragma unroll
        for (int mi = 0; mi < 4; ++mi)
            #pragma unroll
            for (int ni = 0; ni < 2; ++ni)
                acc[mi][ni] = __builtin_amdgcn_mfma_f32_16x16x32_bf16(af[mi], bf[ni],
                                                                      acc[mi][ni], 0, 0, 0);
        __syncthreads();
    }

    int rbase = (lane >> 4) << 2;
    #pragma unroll
    for (int ni = 0; ni < 2; ++ni) {
        int col = ct * BN + c0 + ni * 16 + lrow;
        float bb = b2[col];
        #pragma unroll
        for (int mi = 0; mi < 4; ++mi) {
            #pragma unroll
            for (int j = 0; j < 4; ++j) {
                int row = rt * BM + r0 + mi * 16 + rbase + j;
                if (row < M) {
                    size_t o = (size_t)row * N + col;
                    float v = acc[mi][ni][j] + bb;
                    if (accum) out[o] += v;
                    else       out[o]  = v;
                }
            }
        }
    }
}

// ---------------- host ----------------

extern "C" void kernel_launch(void* const* d_in, const int* in_sizes, int n_in,
                              void* d_out, int out_size, void* d_ws, size_t ws_size,
                              hipStream_t stream) {
    const float* sel_features = (const float*)d_in[0];
    const int*   q            = (const int*)d_in[1];
    const int*   seg          = (const int*)d_in[2];
    const int*   pad_idx      = (const int*)d_in[3];
    const float* coords       = (const float*)d_in[4];
    const float* sel_coors    = (const float*)d_in[5];
    const float* W            = (const float*)d_in[7];
    const float* w1e          = (const float*)d_in[8];
    const float* b1e          = (const float*)d_in[9];
    const float* w2e          = (const float*)d_in[10];
    const float* b2e          = (const float*)d_in[11];
    const float* w1d          = (const float*)d_in[12];
    const float* b1d          = (const float*)d_in[13];
    const float* w2d          = (const float*)d_in[14];
    const float* b2d          = (const float*)d_in[15];

    int npts    = in_sizes[1];
    int num_seg = in_sizes[3];
    int psize3  = in_sizes[7] / (IN_CHANS * EMBED);

    float* out  = (float*)d_out;
    float* out0 = out;                                       // [num_seg, 768]
    float* out1 = out0 + (size_t)num_seg * EMBED;            // sel_features copy
    float* out2 = out1 + (size_t)npts * IN_CHANS;            // sel_coors copy
    float* out3 = out2 + (size_t)npts * 3;                   // [num_seg, 512]

    // ws layout: hE | hD | w2tE | w2tD | segcnt | segsum | notones
    char* wsb = (char*)d_ws;
    __hip_bfloat16* hE   = (__hip_bfloat16*)wsb;
    __hip_bfloat16* hD   = hE + (size_t)num_seg * EMBED;
    __hip_bfloat16* w2tE = hD + (size_t)num_seg * DEC_EMBED;
    __hip_bfloat16* w2tD = w2tE + (size_t)EMBED * EMBED;
    int*   segcnt  = (int*)(w2tD + (size_t)DEC_EMBED * DEC_EMBED);
    float* segsum  = (float*)(segcnt + num_seg);
    int*   notones = (int*)(segsum + num_seg);

    hipMemsetAsync(segcnt, 0, sizeof(int) * (size_t)(2 * num_seg + 1), stream);

    int hcBlocks = 1024, ckBlocks = 1024;
    int ntE = (EMBED / 32) * (EMBED / 32);
    int ntD = (DEC_EMBED / 32) * (DEC_EMBED / 32);
    hc_kernel<<<hcBlocks + ckBlocks + ntE + ntD, NTHREADS, 0, stream>>>(
        coords, w1e, b1e, w1d, b1d, seg, sel_features, sel_coors,
        w2e, w2d, W, hE, hD, w2tE, w2tD, segcnt, segsum, notones, out1, out2,
        hcBlocks, ckBlocks, num_seg, npts, psize3);

    broadcast_kernel<<<2048, NTHREADS, 0, stream>>>(notones, segsum, segcnt,
                                                    pad_idx, out0, num_seg);
    fallback_project_kernel<<<2048, NTHREADS, 0, stream>>>(notones, sel_features, q, seg,
                                                           segcnt, pad_idx, W, out0, npts);

    int rtiles = (num_seg + 127) / 128;
    int nblkE = rtiles * (EMBED / 64);
    int nblkD = rtiles * (DEC_EMBED / 64);
    gemm_lds_kernel<<<nblkE + nblkD, NTHREADS, 0, stream>>>(hE, w2tE, b2e, hD, w2tD, b2d,
                                                            out0, out3, num_seg, nblkE);
}

// Round 18
// 72.771 us; speedup vs baseline: 2.6655x; 1.1182x over previous
//
#include <hip/hip_runtime.h>
#include <hip/hip_bf16.h>
#include <cmath>

#define NTHREADS 256

constexpr int IN_CHANS = 6;
constexpr int EMBED = 768;
constexpr int DEC_EMBED = 512;

typedef __attribute__((ext_vector_type(8))) short short8;
typedef __attribute__((ext_vector_type(4))) float f32x4;

__device__ __forceinline__ void gload_lds16(const short* g, short* l) {
    __builtin_amdgcn_global_load_lds((const __attribute__((address_space(1))) void*)g,
                                     (__attribute__((address_space(3))) void*)l, 16, 0, 0);
}

__device__ __forceinline__ float gelu_f(float x) {
    return 0.5f * x * (1.0f + erff(x * 0.70710678118654752f));
}

// ---- fused hc: 3 block roles ----
// [0, hcBlocks):            gelu h, segcnt+segsum, inv scatter, out1/out2 copies
// [hcBlocks, +ckBlocks):    W==1 streaming check
// [hcBlocks+ckBlocks, ...): w2 transpose tiles

__global__ void hc_kernel(const float* __restrict__ coords,
                          const float* __restrict__ w1e, const float* __restrict__ b1e,
                          const float* __restrict__ w1d, const float* __restrict__ b1d,
                          const int* __restrict__ seg, const int* __restrict__ pad_idx,
                          const float* __restrict__ sel, const float* __restrict__ selc,
                          const float* __restrict__ w2e, const float* __restrict__ w2d,
                          const float* __restrict__ Wproj,
                          __hip_bfloat16* __restrict__ hE, __hip_bfloat16* __restrict__ hD,
                          __hip_bfloat16* __restrict__ w2tE, __hip_bfloat16* __restrict__ w2tD,
                          int* __restrict__ segcnt, float* __restrict__ segsum,
                          int* __restrict__ inv, int* __restrict__ notones,
                          float* __restrict__ out1, float* __restrict__ out2,
                          int hcBlocks, int ckBlocks, int num_seg, int npts, int psize3) {
    __shared__ float tile[32][33];
    int bid = blockIdx.x;
    if (bid >= hcBlocks + ckBlocks) {
        // ---- transpose role ----
        int b = bid - hcBlocks - ckBlocks;
        const float* src; __hip_bfloat16* dst; int n;
        const int ntE = (EMBED / 32) * (EMBED / 32);
        if (b < ntE) { src = w2e; dst = w2tE; n = EMBED; }
        else         { b -= ntE; src = w2d; dst = w2tD; n = DEC_EMBED; }
        int tpr = n / 32;
        int tr = b / tpr, tc = b % tpr;
        int tx = threadIdx.x & 31, ty = threadIdx.x >> 5;
        #pragma unroll
        for (int i = 0; i < 4; ++i)
            tile[ty + 8 * i][tx] = src[(size_t)(tr * 32 + ty + 8 * i) * n + tc * 32 + tx];
        __syncthreads();
        #pragma unroll
        for (int i = 0; i < 4; ++i)
            dst[(size_t)(tc * 32 + ty + 8 * i) * n + tr * 32 + tx] =
                __float2bfloat16(tile[tx][ty + 8 * i]);
        return;
    }
    if (bid >= hcBlocks) {
        // ---- W-check role ----
        int b = bid - hcBlocks;
        const unsigned total4 = (unsigned)psize3 * (IN_CHANS * EMBED / 4);
        const unsigned stride4 = (unsigned)ckBlocks * blockDim.x * 4u;
        const float4* p = reinterpret_cast<const float4*>(Wproj);
        bool bad = false;
        for (unsigned i = ((unsigned)b * blockDim.x + threadIdx.x) * 4u; i < total4;
             i += stride4) {
            float4 v0 = p[i], v1 = p[i + 1], v2 = p[i + 2], v3 = p[i + 3];
            bad |= v0.x != 1.f || v0.y != 1.f || v0.z != 1.f || v0.w != 1.f;
            bad |= v1.x != 1.f || v1.y != 1.f || v1.z != 1.f || v1.w != 1.f;
            bad |= v2.x != 1.f || v2.y != 1.f || v2.z != 1.f || v2.w != 1.f;
            bad |= v3.x != 1.f || v3.y != 1.f || v3.z != 1.f || v3.w != 1.f;
        }
        if (bad) atomicOr(notones, 1);
        return;
    }
    // ---- main role ----
    const unsigned nE8 = (unsigned)num_seg * (EMBED / 8);
    const unsigned nD8 = (unsigned)num_seg * (DEC_EMBED / 8);
    const unsigned t0 = nE8;
    const unsigned t1 = t0 + nD8;
    const unsigned t2 = t1 + (unsigned)npts;                 // counts + rowsum
    const unsigned t2b = t2 + (unsigned)num_seg;             // inv scatter
    const unsigned n14 = (unsigned)npts * IN_CHANS / 4;      // out1 float4s
    const unsigned t3 = t2b + n14;
    const unsigned n24 = (unsigned)npts * 3 / 4;             // out2 float4s
    const unsigned t4 = t3 + n24;
    const unsigned stride = (unsigned)hcBlocks * blockDim.x;
    for (unsigned idx = bid * blockDim.x + threadIdx.x; idx < t4; idx += stride) {
        if (idx < t0) {
            unsigned r = idx / (EMBED / 8), d = (idx % (EMBED / 8)) * 8;
            float c0 = coords[r * 3 + 0], c1 = coords[r * 3 + 1], c2 = coords[r * 3 + 2];
            float4 wa0 = *reinterpret_cast<const float4*>(w1e + 0 * EMBED + d);
            float4 wa1 = *reinterpret_cast<const float4*>(w1e + 0 * EMBED + d + 4);
            float4 wb0 = *reinterpret_cast<const float4*>(w1e + 1 * EMBED + d);
            float4 wb1 = *reinterpret_cast<const float4*>(w1e + 1 * EMBED + d + 4);
            float4 wc0 = *reinterpret_cast<const float4*>(w1e + 2 * EMBED + d);
            float4 wc1 = *reinterpret_cast<const float4*>(w1e + 2 * EMBED + d + 4);
            float4 bb0 = *reinterpret_cast<const float4*>(b1e + d);
            float4 bb1 = *reinterpret_cast<const float4*>(b1e + d + 4);
            union { short8 v; __hip_bfloat16 h[8]; } u;
            #pragma unroll
            for (int i = 0; i < 4; ++i)
                u.h[i] = __float2bfloat16(gelu_f(c0 * (&wa0.x)[i] + c1 * (&wb0.x)[i]
                                               + c2 * (&wc0.x)[i] + (&bb0.x)[i]));
            #pragma unroll
            for (int i = 0; i < 4; ++i)
                u.h[4 + i] = __float2bfloat16(gelu_f(c0 * (&wa1.x)[i] + c1 * (&wb1.x)[i]
                                                   + c2 * (&wc1.x)[i] + (&bb1.x)[i]));
            *reinterpret_cast<short8*>(&hE[(size_t)r * EMBED + d]) = u.v;
        } else if (idx < t1) {
            unsigned j = idx - t0;
            unsigned r = j / (DEC_EMBED / 8), d = (j % (DEC_EMBED / 8)) * 8;
            float c0 = coords[r * 3 + 0], c1 = coords[r * 3 + 1], c2 = coords[r * 3 + 2];
            float4 wa0 = *reinterpret_cast<const float4*>(w1d + 0 * DEC_EMBED + d);
            float4 wa1 = *reinterpret_cast<const float4*>(w1d + 0 * DEC_EMBED + d + 4);
            float4 wb0 = *reinterpret_cast<const float4*>(w1d + 1 * DEC_EMBED + d);
            float4 wb1 = *reinterpret_cast<const float4*>(w1d + 1 * DEC_EMBED + d + 4);
            float4 wc0 = *reinterpret_cast<const float4*>(w1d + 2 * DEC_EMBED + d);
            float4 wc1 = *reinterpret_cast<const float4*>(w1d + 2 * DEC_EMBED + d + 4);
            float4 bb0 = *reinterpret_cast<const float4*>(b1d + d);
            float4 bb1 = *reinterpret_cast<const float4*>(b1d + d + 4);
            union { short8 v; __hip_bfloat16 h[8]; } u;
            #pragma unroll
            for (int i = 0; i < 4; ++i)
                u.h[i] = __float2bfloat16(gelu_f(c0 * (&wa0.x)[i] + c1 * (&wb0.x)[i]
                                               + c2 * (&wc0.x)[i] + (&bb0.x)[i]));
            #pragma unroll
            for (int i = 0; i < 4; ++i)
                u.h[4 + i] = __float2bfloat16(gelu_f(c0 * (&wa1.x)[i] + c1 * (&wb1.x)[i]
                                                   + c2 * (&wc1.x)[i] + (&bb1.x)[i]));
            *reinterpret_cast<short8*>(&hD[(size_t)r * DEC_EMBED + d]) = u.v;
        } else if (idx < t2) {
            int i = (int)(idx - t1);
            int s = seg[i];
            atomicAdd(&segcnt[s], 1);
            const float2* s2 = reinterpret_cast<const float2*>(sel + (size_t)i * IN_CHANS);
            float2 a = s2[0], b = s2[1], c = s2[2];
            unsafeAtomicAdd(&segsum[s], a.x + a.y + b.x + b.y + c.x + c.y);
        } else if (idx < t2b) {
            int s = (int)(idx - t2);
            inv[pad_idx[s]] = s;
        } else if (idx < t3) {
            unsigned j = idx - t2b;
            reinterpret_cast<float4*>(out1)[j] =
                reinterpret_cast<const float4*>(sel)[j];
        } else {
            unsigned j = idx - t3;
            reinterpret_cast<float4*>(out2)[j] =
                reinterpret_cast<const float4*>(selc)[j];
        }
    }
}

// ---- fallback (W != 1, never expected): atomic add of scaled projection ----
// Runs AFTER gemm; gemm wrote pos_emb only (mean=0) when notones set.

__global__ void fallback_project_kernel(const int* __restrict__ notones,
                                        const float* __restrict__ sel,
                                        const int* __restrict__ q,
                                        const int* __restrict__ seg,
                                        const int* __restrict__ segcnt,
                                        const int* __restrict__ pad_idx,
                                        const float* __restrict__ W,
                                        float* __restrict__ out0, int npts) {
    if (*notones == 0) return;
    long total = (long)npts * (EMBED / 4);
    for (long idx = blockIdx.x * (long)blockDim.x + threadIdx.x; idx < total;
         idx += (long)gridDim.x * blockDim.x) {
        int n = (int)(idx / (EMBED / 4));
        int d4 = (int)(idx % (EMBED / 4)) * 4;
        int s = seg[n];
        float invc = 1.0f / (float)max(segcnt[s], 1);
        const float* Wr = W + (size_t)q[n] * IN_CHANS * EMBED + d4;
        float acc[4] = {0.f, 0.f, 0.f, 0.f};
        #pragma unroll
        for (int c = 0; c < IN_CHANS; ++c) {
            float sv = sel[(size_t)n * IN_CHANS + c];
            float4 wv = *reinterpret_cast<const float4*>(Wr + c * EMBED);
            acc[0] += sv * wv.x; acc[1] += sv * wv.y;
            acc[2] += sv * wv.z; acc[3] += sv * wv.w;
        }
        size_t j = (size_t)pad_idx[s];
        #pragma unroll
        for (int i = 0; i < 4; ++i)
            unsafeAtomicAdd(&out0[j * EMBED + d4 + i], acc[i] * invc);
    }
}

// ---- bf16 MFMA GEMM via LDS: enc: out0 = h@w2 + b2 + mean[inv[row]];
//      dec: out3 = h@w2 + b2 ----

__global__ __launch_bounds__(256, 4)
void gemm_lds_kernel(const __hip_bfloat16* __restrict__ hE,
                     const __hip_bfloat16* __restrict__ w2tE,
                     const float* __restrict__ b2e,
                     const __hip_bfloat16* __restrict__ hD,
                     const __hip_bfloat16* __restrict__ w2tD,
                     const float* __restrict__ b2d,
                     const int* __restrict__ notones,
                     const float* __restrict__ segsum,
                     const int* __restrict__ segcnt,
                     const int* __restrict__ inv,
                     float* __restrict__ out0, float* __restrict__ out3,
                     int M, int nblkE) {
    int nblk = gridDim.x;
    int bid = blockIdx.x;
    int q8 = nblk >> 3, r8 = nblk & 7;
    int xcd = bid & 7, idx = bid >> 3;
    int bx = (xcd < r8 ? xcd * (q8 + 1) : r8 * (q8 + 1) + (xcd - r8) * q8) + idx;

    const short* A;
    const short* Bt;
    const float* b2;
    float* out;
    int N, K;
    bool enc;
    if (bx < nblkE) {
        A = (const short*)hE; Bt = (const short*)w2tE; b2 = b2e; out = out0;
        N = EMBED; K = EMBED; enc = true;
    } else {
        bx -= nblkE;
        A = (const short*)hD; Bt = (const short*)w2tD; b2 = b2d; out = out3;
        N = DEC_EMBED; K = DEC_EMBED; enc = false;
    }
    constexpr int BM = 128, BN = 64, BK = 32;
    int ctiles = N / BN;
    int rt = bx / ctiles, ct = bx % ctiles;

    __shared__ short Al[BM * BK];
    __shared__ short Bl[BN * BK];

    int t = threadIdx.x;
    int lane = t & 63;
    int w = t >> 6;
    int wr = w >> 1, wc = w & 1;
    int r0 = wr * 64;
    int c0 = wc * 32;

    int lrow = lane & 15;
    int kgrp = (lane >> 4) << 3;

    int oA = t * 16;
    int rowA0 = oA >> 6;
    int kkA  = (oA & 63) >> 1;
    int rowA1 = rowA0 + 64;
    int rowB = oA >> 6;

    int gA0 = rt * BM + rowA0; if (gA0 >= M) gA0 = M - 1;
    int gA1 = rt * BM + rowA1; if (gA1 >= M) gA1 = M - 1;
    const short* a0p = A + (size_t)gA0 * K + kkA;
    const short* a1p = A + (size_t)gA1 * K + kkA;
    const short* bp  = Bt + (size_t)(ct * BN + rowB) * K + kkA;
    short* la0 = &Al[t * 8];
    short* la1 = &Al[t * 8 + 2048];
    short* lb  = &Bl[t * 8];

    f32x4 acc[4][2];
    #pragma unroll
    for (int mi = 0; mi < 4; ++mi)
        #pragma unroll
        for (int ni = 0; ni < 2; ++ni) acc[mi][ni] = f32x4{0.f, 0.f, 0.f, 0.f};

    for (int k0 = 0; k0 < K; k0 += BK) {
        gload_lds16(a0p + k0, la0);
        gload_lds16(a1p + k0, la1);
        gload_lds16(bp + k0, lb);
        __syncthreads();
        short8 af[4], bf[2];
        #pragma unroll
        for (int mi = 0; mi < 4; ++mi)
            af[mi] = *reinterpret_cast<const short8*>(&Al[(r0 + mi * 16 + lrow) * BK + kgrp]);
        #pragma unroll
        for (int ni = 0; ni < 2; ++ni)
            bf[ni] = *reinterpret_cast<const short8*>(&Bl[(c0 + ni * 16 + lrow) * BK + kgrp]);
        #pragma unroll
        for (int mi = 0; mi < 4; ++mi)
            #pragma unroll
            for (int ni = 0; ni < 2; ++ni)
                acc[mi][ni] = __builtin_amdgcn_mfma_f32_16x16x32_bf16(af[mi], bf[ni],
                                                                      acc[mi][ni], 0, 0, 0);
        __syncthreads();
    }

    int rbase = (lane >> 4) << 2;
    // per-row mean for enc (0 when fallback or dec)
    float mrow[4][4];
    bool fast = enc && (*notones == 0);
    #pragma unroll
    for (int mi = 0; mi < 4; ++mi)
        #pragma unroll
        for (int j = 0; j < 4; ++j) {
            float mv = 0.f;
            int row = rt * BM + r0 + mi * 16 + rbase + j;
            if (fast && row < M) {
                int s = inv[row];
                mv = segsum[s] / (float)max(segcnt[s], 1);
            }
            mrow[mi][j] = mv;
        }
    #pragma unroll
    for (int ni = 0; ni < 2; ++ni) {
        int col = ct * BN + c0 + ni * 16 + lrow;
        float bb = b2[col];
        #pragma unroll
        for (int mi = 0; mi < 4; ++mi) {
            #pragma unroll
            for (int j = 0; j < 4; ++j) {
                int row = rt * BM + r0 + mi * 16 + rbase + j;
                if (row < M) {
                    size_t o = (size_t)row * N + col;
                    out[o] = acc[mi][ni][j] + bb + mrow[mi][j];
                }
            }
        }
    }
}

// ---------------- host ----------------

extern "C" void kernel_launch(void* const* d_in, const int* in_sizes, int n_in,
                              void* d_out, int out_size, void* d_ws, size_t ws_size,
                              hipStream_t stream) {
    const float* sel_features = (const float*)d_in[0];
    const int*   q            = (const int*)d_in[1];
    const int*   seg          = (const int*)d_in[2];
    const int*   pad_idx      = (const int*)d_in[3];
    const float* coords       = (const float*)d_in[4];
    const float* sel_coors    = (const float*)d_in[5];
    const float* W            = (const float*)d_in[7];
    const float* w1e          = (const float*)d_in[8];
    const float* b1e          = (const float*)d_in[9];
    const float* w2e          = (const float*)d_in[10];
    const float* b2e          = (const float*)d_in[11];
    const float* w1d          = (const float*)d_in[12];
    const float* b1d          = (const float*)d_in[13];
    const float* w2d          = (const float*)d_in[14];
    const float* b2d          = (const float*)d_in[15];

    int npts    = in_sizes[1];
    int num_seg = in_sizes[3];
    int psize3  = in_sizes[7] / (IN_CHANS * EMBED);

    float* out  = (float*)d_out;
    float* out0 = out;                                       // [num_seg, 768]
    float* out1 = out0 + (size_t)num_seg * EMBED;            // sel_features copy
    float* out2 = out1 + (size_t)npts * IN_CHANS;            // sel_coors copy
    float* out3 = out2 + (size_t)npts * 3;                   // [num_seg, 512]

    // ws layout: hE | hD | w2tE | w2tD | segcnt | segsum | notones | inv
    char* wsb = (char*)d_ws;
    __hip_bfloat16* hE   = (__hip_bfloat16*)wsb;
    __hip_bfloat16* hD   = hE + (size_t)num_seg * EMBED;
    __hip_bfloat16* w2tE = hD + (size_t)num_seg * DEC_EMBED;
    __hip_bfloat16* w2tD = w2tE + (size_t)EMBED * EMBED;
    int*   segcnt  = (int*)(w2tD + (size_t)DEC_EMBED * DEC_EMBED);
    float* segsum  = (float*)(segcnt + num_seg);
    int*   notones = (int*)(segsum + num_seg);
    int*   inv     = notones + 1;            // [num_seg], fully written by scatter

    hipMemsetAsync(segcnt, 0, sizeof(int) * (size_t)(2 * num_seg + 1), stream);

    int hcBlocks = 1024, ckBlocks = 1024;
    int ntE = (EMBED / 32) * (EMBED / 32);
    int ntD = (DEC_EMBED / 32) * (DEC_EMBED / 32);
    hc_kernel<<<hcBlocks + ckBlocks + ntE + ntD, NTHREADS, 0, stream>>>(
        coords, w1e, b1e, w1d, b1d, seg, pad_idx, sel_features, sel_coors,
        w2e, w2d, W, hE, hD, w2tE, w2tD, segcnt, segsum, inv, notones, out1, out2,
        hcBlocks, ckBlocks, num_seg, npts, psize3);

    int rtiles = (num_seg + 127) / 128;
    int nblkE = rtiles * (EMBED / 64);
    int nblkD = rtiles * (DEC_EMBED / 64);
    gemm_lds_kernel<<<nblkE + nblkD, NTHREADS, 0, stream>>>(hE, w2tE, b2e, hD, w2tD, b2d,
                                                            notones, segsum, segcnt, inv,
                                                            out0, out3, num_seg, nblkE);

    fallback_project_kernel<<<2048, NTHREADS, 0, stream>>>(notones, sel_features, q, seg,
                                                           segcnt, pad_idx, W, out0, npts);
}

// Round 19
// 72.541 us; speedup vs baseline: 2.6740x; 1.0032x over previous
//
#include <hip/hip_runtime.h>
#include <hip/hip_bf16.h>
#include <cmath>

#define NTHREADS 256

constexpr int IN_CHANS = 6;
constexpr int EMBED = 768;
constexpr int DEC_EMBED = 512;

typedef __attribute__((ext_vector_type(8))) short short8;
typedef __attribute__((ext_vector_type(4))) float f32x4;

__device__ __forceinline__ void gload_lds16(const short* g, short* l) {
    __builtin_amdgcn_global_load_lds((const __attribute__((address_space(1))) void*)g,
                                     (__attribute__((address_space(3))) void*)l, 16, 0, 0);
}

__device__ __forceinline__ float gelu_f(float x) {
    return 0.5f * x * (1.0f + erff(x * 0.70710678118654752f));
}

// ---- fused hc: 3 block roles ----
// [0, hcBlocks):            gelu h, segcnt+segsum, inv scatter, out1/out2 copies
// [hcBlocks, +ckBlocks):    W==1 streaming check
// [hcBlocks+ckBlocks, ...): w2 transpose tiles

__global__ void hc_kernel(const float* __restrict__ coords,
                          const float* __restrict__ w1e, const float* __restrict__ b1e,
                          const float* __restrict__ w1d, const float* __restrict__ b1d,
                          const int* __restrict__ seg, const int* __restrict__ pad_idx,
                          const float* __restrict__ sel, const float* __restrict__ selc,
                          const float* __restrict__ w2e, const float* __restrict__ w2d,
                          const float* __restrict__ Wproj,
                          __hip_bfloat16* __restrict__ hE, __hip_bfloat16* __restrict__ hD,
                          __hip_bfloat16* __restrict__ w2tE, __hip_bfloat16* __restrict__ w2tD,
                          int* __restrict__ segcnt, float* __restrict__ segsum,
                          int* __restrict__ inv, int* __restrict__ notones,
                          float* __restrict__ out1, float* __restrict__ out2,
                          int hcBlocks, int ckBlocks, int num_seg, int npts, int psize3) {
    __shared__ float tile[32][33];
    int bid = blockIdx.x;
    if (bid >= hcBlocks + ckBlocks) {
        // ---- transpose role ----
        int b = bid - hcBlocks - ckBlocks;
        const float* src; __hip_bfloat16* dst; int n;
        const int ntE = (EMBED / 32) * (EMBED / 32);
        if (b < ntE) { src = w2e; dst = w2tE; n = EMBED; }
        else         { b -= ntE; src = w2d; dst = w2tD; n = DEC_EMBED; }
        int tpr = n / 32;
        int tr = b / tpr, tc = b % tpr;
        int tx = threadIdx.x & 31, ty = threadIdx.x >> 5;
        #pragma unroll
        for (int i = 0; i < 4; ++i)
            tile[ty + 8 * i][tx] = src[(size_t)(tr * 32 + ty + 8 * i) * n + tc * 32 + tx];
        __syncthreads();
        #pragma unroll
        for (int i = 0; i < 4; ++i)
            dst[(size_t)(tc * 32 + ty + 8 * i) * n + tr * 32 + tx] =
                __float2bfloat16(tile[tx][ty + 8 * i]);
        return;
    }
    if (bid >= hcBlocks) {
        // ---- W-check role ----
        int b = bid - hcBlocks;
        const unsigned total4 = (unsigned)psize3 * (IN_CHANS * EMBED / 4);
        const unsigned stride4 = (unsigned)ckBlocks * blockDim.x * 4u;
        const float4* p = reinterpret_cast<const float4*>(Wproj);
        bool bad = false;
        for (unsigned i = ((unsigned)b * blockDim.x + threadIdx.x) * 4u; i < total4;
             i += stride4) {
            float4 v0 = p[i], v1 = p[i + 1], v2 = p[i + 2], v3 = p[i + 3];
            bad |= v0.x != 1.f || v0.y != 1.f || v0.z != 1.f || v0.w != 1.f;
            bad |= v1.x != 1.f || v1.y != 1.f || v1.z != 1.f || v1.w != 1.f;
            bad |= v2.x != 1.f || v2.y != 1.f || v2.z != 1.f || v2.w != 1.f;
            bad |= v3.x != 1.f || v3.y != 1.f || v3.z != 1.f || v3.w != 1.f;
        }
        if (bad) atomicOr(notones, 1);
        return;
    }
    // ---- main role ----
    const unsigned nE8 = (unsigned)num_seg * (EMBED / 8);
    const unsigned nD8 = (unsigned)num_seg * (DEC_EMBED / 8);
    const unsigned t0 = nE8;
    const unsigned t1 = t0 + nD8;
    const unsigned t2 = t1 + (unsigned)npts;                 // counts + rowsum
    const unsigned t2b = t2 + (unsigned)num_seg;             // inv scatter
    const unsigned n14 = (unsigned)npts * IN_CHANS / 4;      // out1 float4s
    const unsigned t3 = t2b + n14;
    const unsigned n24 = (unsigned)npts * 3 / 4;             // out2 float4s
    const unsigned t4 = t3 + n24;
    const unsigned stride = (unsigned)hcBlocks * blockDim.x;
    for (unsigned idx = bid * blockDim.x + threadIdx.x; idx < t4; idx += stride) {
        if (idx < t0) {
            unsigned r = idx / (EMBED / 8), d = (idx % (EMBED / 8)) * 8;
            float c0 = coords[r * 3 + 0], c1 = coords[r * 3 + 1], c2 = coords[r * 3 + 2];
            float4 wa0 = *reinterpret_cast<const float4*>(w1e + 0 * EMBED + d);
            float4 wa1 = *reinterpret_cast<const float4*>(w1e + 0 * EMBED + d + 4);
            float4 wb0 = *reinterpret_cast<const float4*>(w1e + 1 * EMBED + d);
            float4 wb1 = *reinterpret_cast<const float4*>(w1e + 1 * EMBED + d + 4);
            float4 wc0 = *reinterpret_cast<const float4*>(w1e + 2 * EMBED + d);
            float4 wc1 = *reinterpret_cast<const float4*>(w1e + 2 * EMBED + d + 4);
            float4 bb0 = *reinterpret_cast<const float4*>(b1e + d);
            float4 bb1 = *reinterpret_cast<const float4*>(b1e + d + 4);
            union { short8 v; __hip_bfloat16 h[8]; } u;
            #pragma unroll
            for (int i = 0; i < 4; ++i)
                u.h[i] = __float2bfloat16(gelu_f(c0 * (&wa0.x)[i] + c1 * (&wb0.x)[i]
                                               + c2 * (&wc0.x)[i] + (&bb0.x)[i]));
            #pragma unroll
            for (int i = 0; i < 4; ++i)
                u.h[4 + i] = __float2bfloat16(gelu_f(c0 * (&wa1.x)[i] + c1 * (&wb1.x)[i]
                                                   + c2 * (&wc1.x)[i] + (&bb1.x)[i]));
            *reinterpret_cast<short8*>(&hE[(size_t)r * EMBED + d]) = u.v;
        } else if (idx < t1) {
            unsigned j = idx - t0;
            unsigned r = j / (DEC_EMBED / 8), d = (j % (DEC_EMBED / 8)) * 8;
            float c0 = coords[r * 3 + 0], c1 = coords[r * 3 + 1], c2 = coords[r * 3 + 2];
            float4 wa0 = *reinterpret_cast<const float4*>(w1d + 0 * DEC_EMBED + d);
            float4 wa1 = *reinterpret_cast<const float4*>(w1d + 0 * DEC_EMBED + d + 4);
            float4 wb0 = *reinterpret_cast<const float4*>(w1d + 1 * DEC_EMBED + d);
            float4 wb1 = *reinterpret_cast<const float4*>(w1d + 1 * DEC_EMBED + d + 4);
            float4 wc0 = *reinterpret_cast<const float4*>(w1d + 2 * DEC_EMBED + d);
            float4 wc1 = *reinterpret_cast<const float4*>(w1d + 2 * DEC_EMBED + d + 4);
            float4 bb0 = *reinterpret_cast<const float4*>(b1d + d);
            float4 bb1 = *reinterpret_cast<const float4*>(b1d + d + 4);
            union { short8 v; __hip_bfloat16 h[8]; } u;
            #pragma unroll
            for (int i = 0; i < 4; ++i)
                u.h[i] = __float2bfloat16(gelu_f(c0 * (&wa0.x)[i] + c1 * (&wb0.x)[i]
                                               + c2 * (&wc0.x)[i] + (&bb0.x)[i]));
            #pragma unroll
            for (int i = 0; i < 4; ++i)
                u.h[4 + i] = __float2bfloat16(gelu_f(c0 * (&wa1.x)[i] + c1 * (&wb1.x)[i]
                                                   + c2 * (&wc1.x)[i] + (&bb1.x)[i]));
            *reinterpret_cast<short8*>(&hD[(size_t)r * DEC_EMBED + d]) = u.v;
        } else if (idx < t2) {
            int i = (int)(idx - t1);
            int s = seg[i];
            atomicAdd(&segcnt[s], 1);
            const float2* s2 = reinterpret_cast<const float2*>(sel + (size_t)i * IN_CHANS);
            float2 a = s2[0], b = s2[1], c = s2[2];
            unsafeAtomicAdd(&segsum[s], a.x + a.y + b.x + b.y + c.x + c.y);
        } else if (idx < t2b) {
            int s = (int)(idx - t2);
            inv[pad_idx[s]] = s;
        } else if (idx < t3) {
            unsigned j = idx - t2b;
            reinterpret_cast<float4*>(out1)[j] =
                reinterpret_cast<const float4*>(sel)[j];
        } else {
            unsigned j = idx - t3;
            reinterpret_cast<float4*>(out2)[j] =
                reinterpret_cast<const float4*>(selc)[j];
        }
    }
}

// ---- fallback (W != 1, never expected): atomic add of scaled projection ----

__global__ void fallback_project_kernel(const int* __restrict__ notones,
                                        const float* __restrict__ sel,
                                        const int* __restrict__ q,
                                        const int* __restrict__ seg,
                                        const int* __restrict__ segcnt,
                                        const int* __restrict__ pad_idx,
                                        const float* __restrict__ W,
                                        float* __restrict__ out0, int npts) {
    if (*notones == 0) return;
    long total = (long)npts * (EMBED / 4);
    for (long idx = blockIdx.x * (long)blockDim.x + threadIdx.x; idx < total;
         idx += (long)gridDim.x * blockDim.x) {
        int n = (int)(idx / (EMBED / 4));
        int d4 = (int)(idx % (EMBED / 4)) * 4;
        int s = seg[n];
        float invc = 1.0f / (float)max(segcnt[s], 1);
        const float* Wr = W + (size_t)q[n] * IN_CHANS * EMBED + d4;
        float acc[4] = {0.f, 0.f, 0.f, 0.f};
        #pragma unroll
        for (int c = 0; c < IN_CHANS; ++c) {
            float sv = sel[(size_t)n * IN_CHANS + c];
            float4 wv = *reinterpret_cast<const float4*>(Wr + c * EMBED);
            acc[0] += sv * wv.x; acc[1] += sv * wv.y;
            acc[2] += sv * wv.z; acc[3] += sv * wv.w;
        }
        size_t j = (size_t)pad_idx[s];
        #pragma unroll
        for (int i = 0; i < 4; ++i)
            unsafeAtomicAdd(&out0[j * EMBED + d4 + i], acc[i] * invc);
    }
}

// ---- bf16 MFMA GEMM via LDS, BK=64: enc: out0 = h@w2 + b2 + mean[inv[row]];
//      dec: out3 = h@w2 + b2 ----

__global__ __launch_bounds__(256, 4)
void gemm_lds_kernel(const __hip_bfloat16* __restrict__ hE,
                     const __hip_bfloat16* __restrict__ w2tE,
                     const float* __restrict__ b2e,
                     const __hip_bfloat16* __restrict__ hD,
                     const __hip_bfloat16* __restrict__ w2tD,
                     const float* __restrict__ b2d,
                     const int* __restrict__ notones,
                     const float* __restrict__ segsum,
                     const int* __restrict__ segcnt,
                     const int* __restrict__ inv,
                     float* __restrict__ out0, float* __restrict__ out3,
                     int M, int nblkE) {
    int nblk = gridDim.x;
    int bid = blockIdx.x;
    int q8 = nblk >> 3, r8 = nblk & 7;
    int xcd = bid & 7, idx = bid >> 3;
    int bx = (xcd < r8 ? xcd * (q8 + 1) : r8 * (q8 + 1) + (xcd - r8) * q8) + idx;

    const short* A;
    const short* Bt;
    const float* b2;
    float* out;
    int N, K;
    bool enc;
    if (bx < nblkE) {
        A = (const short*)hE; Bt = (const short*)w2tE; b2 = b2e; out = out0;
        N = EMBED; K = EMBED; enc = true;
    } else {
        bx -= nblkE;
        A = (const short*)hD; Bt = (const short*)w2tD; b2 = b2d; out = out3;
        N = DEC_EMBED; K = DEC_EMBED; enc = false;
    }
    constexpr int BM = 128, BN = 64, BK = 64;
    int ctiles = N / BN;
    int rt = bx / ctiles, ct = bx % ctiles;

    __shared__ short Al[BM * BK];   // 16 KB, row-major [128][64]
    __shared__ short Bl[BN * BK];   //  8 KB, row-major [64][64]

    int t = threadIdx.x;
    int lane = t & 63;
    int w = t >> 6;
    int wr = w >> 1, wc = w & 1;
    int r0 = wr * 64;
    int c0 = wc * 32;

    int lrow = lane & 15;
    int kgrp = (lane >> 4) << 3;

    // staging: issue i covers shorts [i*2048 + t*8, +8); row = i*32 + t/8,
    // col = (t&7)*8 within the [*, 64] tile.
    int srow = t >> 3;
    int scol = (t & 7) * 8;

    int gA[4];
    #pragma unroll
    for (int i = 0; i < 4; ++i) {
        int r = rt * BM + i * 32 + srow;
        gA[i] = (r < M) ? r : M - 1;
    }
    const short* ap[4];
    #pragma unroll
    for (int i = 0; i < 4; ++i) ap[i] = A + (size_t)gA[i] * K + scol;
    const short* bp[2];
    #pragma unroll
    for (int i = 0; i < 2; ++i)
        bp[i] = Bt + (size_t)(ct * BN + i * 32 + srow) * K + scol;
    short* la[4];
    #pragma unroll
    for (int i = 0; i < 4; ++i) la[i] = &Al[i * 2048 + t * 8];
    short* lb[2];
    #pragma unroll
    for (int i = 0; i < 2; ++i) lb[i] = &Bl[i * 2048 + t * 8];

    f32x4 acc[4][2];
    #pragma unroll
    for (int mi = 0; mi < 4; ++mi)
        #pragma unroll
        for (int ni = 0; ni < 2; ++ni) acc[mi][ni] = f32x4{0.f, 0.f, 0.f, 0.f};

    for (int k0 = 0; k0 < K; k0 += BK) {
        #pragma unroll
        for (int i = 0; i < 4; ++i) gload_lds16(ap[i] + k0, la[i]);
        #pragma unroll
        for (int i = 0; i < 2; ++i) gload_lds16(bp[i] + k0, lb[i]);
        __syncthreads();
        #pragma unroll
        for (int ks = 0; ks < 2; ++ks) {
            short8 af[4], bf[2];
            #pragma unroll
            for (int mi = 0; mi < 4; ++mi)
                af[mi] = *reinterpret_cast<const short8*>(
                    &Al[(r0 + mi * 16 + lrow) * BK + ks * 32 + kgrp]);
            #pragma unroll
            for (int ni = 0; ni < 2; ++ni)
                bf[ni] = *reinterpret_cast<const short8*>(
                    &Bl[(c0 + ni * 16 + lrow) * BK + ks * 32 + kgrp]);
            #pragma unroll
            for (int mi = 0; mi < 4; ++mi)
                #pragma unroll
                for (int ni = 0; ni < 2; ++ni)
                    acc[mi][ni] = __builtin_amdgcn_mfma_f32_16x16x32_bf16(af[mi], bf[ni],
                                                                          acc[mi][ni],
                                                                          0, 0, 0);
        }
        __syncthreads();
    }

    int rbase = (lane >> 4) << 2;
    float mrow[4][4];
    bool fast = enc && (*notones == 0);
    #pragma unroll
    for (int mi = 0; mi < 4; ++mi)
        #pragma unroll
        for (int j = 0; j < 4; ++j) {
            float mv = 0.f;
            int row = rt * BM + r0 + mi * 16 + rbase + j;
            if (fast && row < M) {
                int s = inv[row];
                mv = segsum[s] / (float)max(segcnt[s], 1);
            }
            mrow[mi][j] = mv;
        }
    #pragma unroll
    for (int ni = 0; ni < 2; ++ni) {
        int col = ct * BN + c0 + ni * 16 + lrow;
        float bb = b2[col];
        #pragma unroll
        for (int mi = 0; mi < 4; ++mi) {
            #pragma unroll
            for (int j = 0; j < 4; ++j) {
                int row = rt * BM + r0 + mi * 16 + rbase + j;
                if (row < M) {
                    size_t o = (size_t)row * N + col;
                    out[o] = acc[mi][ni][j] + bb + mrow[mi][j];
                }
            }
        }
    }
}

// ---------------- host ----------------

extern "C" void kernel_launch(void* const* d_in, const int* in_sizes, int n_in,
                              void* d_out, int out_size, void* d_ws, size_t ws_size,
                              hipStream_t stream) {
    const float* sel_features = (const float*)d_in[0];
    const int*   q            = (const int*)d_in[1];
    const int*   seg          = (const int*)d_in[2];
    const int*   pad_idx      = (const int*)d_in[3];
    const float* coords       = (const float*)d_in[4];
    const float* sel_coors    = (const float*)d_in[5];
    const float* W            = (const float*)d_in[7];
    const float* w1e          = (const float*)d_in[8];
    const float* b1e          = (const float*)d_in[9];
    const float* w2e          = (const float*)d_in[10];
    const float* b2e          = (const float*)d_in[11];
    const float* w1d          = (const float*)d_in[12];
    const float* b1d          = (const float*)d_in[13];
    const float* w2d          = (const float*)d_in[14];
    const float* b2d          = (const float*)d_in[15];

    int npts    = in_sizes[1];
    int num_seg = in_sizes[3];
    int psize3  = in_sizes[7] / (IN_CHANS * EMBED);

    float* out  = (float*)d_out;
    float* out0 = out;                                       // [num_seg, 768]
    float* out1 = out0 + (size_t)num_seg * EMBED;            // sel_features copy
    float* out2 = out1 + (size_t)npts * IN_CHANS;            // sel_coors copy
    float* out3 = out2 + (size_t)npts * 3;                   // [num_seg, 512]

    // ws layout: hE | hD | w2tE | w2tD | segcnt | segsum | notones | inv
    char* wsb = (char*)d_ws;
    __hip_bfloat16* hE   = (__hip_bfloat16*)wsb;
    __hip_bfloat16* hD   = hE + (size_t)num_seg * EMBED;
    __hip_bfloat16* w2tE = hD + (size_t)num_seg * DEC_EMBED;
    __hip_bfloat16* w2tD = w2tE + (size_t)EMBED * EMBED;
    int*   segcnt  = (int*)(w2tD + (size_t)DEC_EMBED * DEC_EMBED);
    float* segsum  = (float*)(segcnt + num_seg);
    int*   notones = (int*)(segsum + num_seg);
    int*   inv     = notones + 1;            // [num_seg], fully written by scatter

    hipMemsetAsync(segcnt, 0, sizeof(int) * (size_t)(2 * num_seg + 1), stream);

    int hcBlocks = 1024, ckBlocks = 1024;
    int ntE = (EMBED / 32) * (EMBED / 32);
    int ntD = (DEC_EMBED / 32) * (DEC_EMBED / 32);
    hc_kernel<<<hcBlocks + ckBlocks + ntE + ntD, NTHREADS, 0, stream>>>(
        coords, w1e, b1e, w1d, b1d, seg, pad_idx, sel_features, sel_coors,
        w2e, w2d, W, hE, hD, w2tE, w2tD, segcnt, segsum, inv, notones, out1, out2,
        hcBlocks, ckBlocks, num_seg, npts, psize3);

    int rtiles = (num_seg + 127) / 128;
    int nblkE = rtiles * (EMBED / 64);
    int nblkD = rtiles * (DEC_EMBED / 64);
    gemm_lds_kernel<<<nblkE + nblkD, NTHREADS, 0, stream>>>(hE, w2tE, b2e, hD, w2tD, b2d,
                                                            notones, segsum, segcnt, inv,
                                                            out0, out3, num_seg, nblkE);

    fallback_project_kernel<<<2048, NTHREADS, 0, stream>>>(notones, sel_features, q, seg,
                                                           segcnt, pad_idx, W, out0, npts);
}

// Round 20
// 71.959 us; speedup vs baseline: 2.6956x; 1.0081x over previous
//
#include <hip/hip_runtime.h>
#include <hip/hip_bf16.h>
#include <cmath>

#define NTHREADS 256

constexpr int IN_CHANS = 6;
constexpr int EMBED = 768;
constexpr int DEC_EMBED = 512;

typedef __attribute__((ext_vector_type(8))) short short8;
typedef __attribute__((ext_vector_type(4))) float f32x4;

__device__ __forceinline__ void gload_lds16(const short* g, short* l) {
    __builtin_amdgcn_global_load_lds((const __attribute__((address_space(1))) void*)g,
                                     (__attribute__((address_space(3))) void*)l, 16, 0, 0);
}

__device__ __forceinline__ float gelu_f(float x) {
    return 0.5f * x * (1.0f + erff(x * 0.70710678118654752f));
}

// ---- fused hc: 3 block roles ----

__global__ void hc_kernel(const float* __restrict__ coords,
                          const float* __restrict__ w1e, const float* __restrict__ b1e,
                          const float* __restrict__ w1d, const float* __restrict__ b1d,
                          const int* __restrict__ seg, const int* __restrict__ pad_idx,
                          const float* __restrict__ sel, const float* __restrict__ selc,
                          const float* __restrict__ w2e, const float* __restrict__ w2d,
                          const float* __restrict__ Wproj,
                          __hip_bfloat16* __restrict__ hE, __hip_bfloat16* __restrict__ hD,
                          __hip_bfloat16* __restrict__ w2tE, __hip_bfloat16* __restrict__ w2tD,
                          int* __restrict__ segcnt, float* __restrict__ segsum,
                          int* __restrict__ inv, int* __restrict__ notones,
                          float* __restrict__ out1, float* __restrict__ out2,
                          int hcBlocks, int ckBlocks, int num_seg, int npts, int psize3) {
    __shared__ float tile[32][33];
    int bid = blockIdx.x;
    if (bid >= hcBlocks + ckBlocks) {
        // ---- transpose role ----
        int b = bid - hcBlocks - ckBlocks;
        const float* src; __hip_bfloat16* dst; int n;
        const int ntE = (EMBED / 32) * (EMBED / 32);
        if (b < ntE) { src = w2e; dst = w2tE; n = EMBED; }
        else         { b -= ntE; src = w2d; dst = w2tD; n = DEC_EMBED; }
        int tpr = n / 32;
        int tr = b / tpr, tc = b % tpr;
        int tx = threadIdx.x & 31, ty = threadIdx.x >> 5;
        #pragma unroll
        for (int i = 0; i < 4; ++i)
            tile[ty + 8 * i][tx] = src[(size_t)(tr * 32 + ty + 8 * i) * n + tc * 32 + tx];
        __syncthreads();
        #pragma unroll
        for (int i = 0; i < 4; ++i)
            dst[(size_t)(tc * 32 + ty + 8 * i) * n + tr * 32 + tx] =
                __float2bfloat16(tile[tx][ty + 8 * i]);
        return;
    }
    if (bid >= hcBlocks) {
        // ---- W-check role ----
        int b = bid - hcBlocks;
        const unsigned total4 = (unsigned)psize3 * (IN_CHANS * EMBED / 4);
        const unsigned stride4 = (unsigned)ckBlocks * blockDim.x * 4u;
        const float4* p = reinterpret_cast<const float4*>(Wproj);
        bool bad = false;
        for (unsigned i = ((unsigned)b * blockDim.x + threadIdx.x) * 4u; i < total4;
             i += stride4) {
            float4 v0 = p[i], v1 = p[i + 1], v2 = p[i + 2], v3 = p[i + 3];
            bad |= v0.x != 1.f || v0.y != 1.f || v0.z != 1.f || v0.w != 1.f;
            bad |= v1.x != 1.f || v1.y != 1.f || v1.z != 1.f || v1.w != 1.f;
            bad |= v2.x != 1.f || v2.y != 1.f || v2.z != 1.f || v2.w != 1.f;
            bad |= v3.x != 1.f || v3.y != 1.f || v3.z != 1.f || v3.w != 1.f;
        }
        if (bad) atomicOr(notones, 1);
        return;
    }
    // ---- main role ----
    const unsigned nE8 = (unsigned)num_seg * (EMBED / 8);
    const unsigned nD8 = (unsigned)num_seg * (DEC_EMBED / 8);
    const unsigned t0 = nE8;
    const unsigned t1 = t0 + nD8;
    const unsigned t2 = t1 + (unsigned)npts;
    const unsigned t2b = t2 + (unsigned)num_seg;
    const unsigned n14 = (unsigned)npts * IN_CHANS / 4;
    const unsigned t3 = t2b + n14;
    const unsigned n24 = (unsigned)npts * 3 / 4;
    const unsigned t4 = t3 + n24;
    const unsigned stride = (unsigned)hcBlocks * blockDim.x;
    for (unsigned idx = bid * blockDim.x + threadIdx.x; idx < t4; idx += stride) {
        if (idx < t0) {
            unsigned r = idx / (EMBED / 8), d = (idx % (EMBED / 8)) * 8;
            float c0 = coords[r * 3 + 0], c1 = coords[r * 3 + 1], c2 = coords[r * 3 + 2];
            float4 wa0 = *reinterpret_cast<const float4*>(w1e + 0 * EMBED + d);
            float4 wa1 = *reinterpret_cast<const float4*>(w1e + 0 * EMBED + d + 4);
            float4 wb0 = *reinterpret_cast<const float4*>(w1e + 1 * EMBED + d);
            float4 wb1 = *reinterpret_cast<const float4*>(w1e + 1 * EMBED + d + 4);
            float4 wc0 = *reinterpret_cast<const float4*>(w1e + 2 * EMBED + d);
            float4 wc1 = *reinterpret_cast<const float4*>(w1e + 2 * EMBED + d + 4);
            float4 bb0 = *reinterpret_cast<const float4*>(b1e + d);
            float4 bb1 = *reinterpret_cast<const float4*>(b1e + d + 4);
            union { short8 v; __hip_bfloat16 h[8]; } u;
            #pragma unroll
            for (int i = 0; i < 4; ++i)
                u.h[i] = __float2bfloat16(gelu_f(c0 * (&wa0.x)[i] + c1 * (&wb0.x)[i]
                                               + c2 * (&wc0.x)[i] + (&bb0.x)[i]));
            #pragma unroll
            for (int i = 0; i < 4; ++i)
                u.h[4 + i] = __float2bfloat16(gelu_f(c0 * (&wa1.x)[i] + c1 * (&wb1.x)[i]
                                                   + c2 * (&wc1.x)[i] + (&bb1.x)[i]));
            *reinterpret_cast<short8*>(&hE[(size_t)r * EMBED + d]) = u.v;
        } else if (idx < t1) {
            unsigned j = idx - t0;
            unsigned r = j / (DEC_EMBED / 8), d = (j % (DEC_EMBED / 8)) * 8;
            float c0 = coords[r * 3 + 0], c1 = coords[r * 3 + 1], c2 = coords[r * 3 + 2];
            float4 wa0 = *reinterpret_cast<const float4*>(w1d + 0 * DEC_EMBED + d);
            float4 wa1 = *reinterpret_cast<const float4*>(w1d + 0 * DEC_EMBED + d + 4);
            float4 wb0 = *reinterpret_cast<const float4*>(w1d + 1 * DEC_EMBED + d);
            float4 wb1 = *reinterpret_cast<const float4*>(w1d + 1 * DEC_EMBED + d + 4);
            float4 wc0 = *reinterpret_cast<const float4*>(w1d + 2 * DEC_EMBED + d);
            float4 wc1 = *reinterpret_cast<const float4*>(w1d + 2 * DEC_EMBED + d + 4);
            float4 bb0 = *reinterpret_cast<const float4*>(b1d + d);
            float4 bb1 = *reinterpret_cast<const float4*>(b1d + d + 4);
            union { short8 v; __hip_bfloat16 h[8]; } u;
            #pragma unroll
            for (int i = 0; i < 4; ++i)
                u.h[i] = __float2bfloat16(gelu_f(c0 * (&wa0.x)[i] + c1 * (&wb0.x)[i]
                                               + c2 * (&wc0.x)[i] + (&bb0.x)[i]));
            #pragma unroll
            for (int i = 0; i < 4; ++i)
                u.h[4 + i] = __float2bfloat16(gelu_f(c0 * (&wa1.x)[i] + c1 * (&wb1.x)[i]
                                                   + c2 * (&wc1.x)[i] + (&bb1.x)[i]));
            *reinterpret_cast<short8*>(&hD[(size_t)r * DEC_EMBED + d]) = u.v;
        } else if (idx < t2) {
            int i = (int)(idx - t1);
            int s = seg[i];
            atomicAdd(&segcnt[s], 1);
            const float2* s2 = reinterpret_cast<const float2*>(sel + (size_t)i * IN_CHANS);
            float2 a = s2[0], b = s2[1], c = s2[2];
            unsafeAtomicAdd(&segsum[s], a.x + a.y + b.x + b.y + c.x + c.y);
        } else if (idx < t2b) {
            int s = (int)(idx - t2);
            inv[pad_idx[s]] = s;
        } else if (idx < t3) {
            unsigned j = idx - t2b;
            reinterpret_cast<float4*>(out1)[j] =
                reinterpret_cast<const float4*>(sel)[j];
        } else {
            unsigned j = idx - t3;
            reinterpret_cast<float4*>(out2)[j] =
                reinterpret_cast<const float4*>(selc)[j];
        }
    }
}

// ---- fallback (W != 1, never expected): atomic add of scaled projection ----

__global__ void fallback_project_kernel(const int* __restrict__ notones,
                                        const float* __restrict__ sel,
                                        const int* __restrict__ q,
                                        const int* __restrict__ seg,
                                        const int* __restrict__ segcnt,
                                        const int* __restrict__ pad_idx,
                                        const float* __restrict__ W,
                                        float* __restrict__ out0, int npts) {
    if (*notones == 0) return;
    long total = (long)npts * (EMBED / 4);
    for (long idx = blockIdx.x * (long)blockDim.x + threadIdx.x; idx < total;
         idx += (long)gridDim.x * blockDim.x) {
        int n = (int)(idx / (EMBED / 4));
        int d4 = (int)(idx % (EMBED / 4)) * 4;
        int s = seg[n];
        float invc = 1.0f / (float)max(segcnt[s], 1);
        const float* Wr = W + (size_t)q[n] * IN_CHANS * EMBED + d4;
        float acc[4] = {0.f, 0.f, 0.f, 0.f};
        #pragma unroll
        for (int c = 0; c < IN_CHANS; ++c) {
            float sv = sel[(size_t)n * IN_CHANS + c];
            float4 wv = *reinterpret_cast<const float4*>(Wr + c * EMBED);
            acc[0] += sv * wv.x; acc[1] += sv * wv.y;
            acc[2] += sv * wv.z; acc[3] += sv * wv.w;
        }
        size_t j = (size_t)pad_idx[s];
        #pragma unroll
        for (int i = 0; i < 4; ++i)
            unsafeAtomicAdd(&out0[j * EMBED + d4 + i], acc[i] * invc);
    }
}

// ---- bf16 MFMA GEMM via LDS, BM=64 BN=64 BK=64 (high TLP) ----
// enc: out0 = h@w2 + b2 + mean[inv[row]]; dec: out3 = h@w2 + b2.
// 4 waves 2x2, wave owns 32x32 (2x2 frags of 16x16x32).

__global__ __launch_bounds__(256, 6)
void gemm_lds_kernel(const __hip_bfloat16* __restrict__ hE,
                     const __hip_bfloat16* __restrict__ w2tE,
                     const float* __restrict__ b2e,
                     const __hip_bfloat16* __restrict__ hD,
                     const __hip_bfloat16* __restrict__ w2tD,
                     const float* __restrict__ b2d,
                     const int* __restrict__ notones,
                     const float* __restrict__ segsum,
                     const int* __restrict__ segcnt,
                     const int* __restrict__ inv,
                     float* __restrict__ out0, float* __restrict__ out3,
                     int M, int nblkE) {
    int nblk = gridDim.x;
    int bid = blockIdx.x;
    int q8 = nblk >> 3, r8 = nblk & 7;
    int xcd = bid & 7, idx = bid >> 3;
    int bx = (xcd < r8 ? xcd * (q8 + 1) : r8 * (q8 + 1) + (xcd - r8) * q8) + idx;

    const short* A;
    const short* Bt;
    const float* b2;
    float* out;
    int N, K;
    bool enc;
    if (bx < nblkE) {
        A = (const short*)hE; Bt = (const short*)w2tE; b2 = b2e; out = out0;
        N = EMBED; K = EMBED; enc = true;
    } else {
        bx -= nblkE;
        A = (const short*)hD; Bt = (const short*)w2tD; b2 = b2d; out = out3;
        N = DEC_EMBED; K = DEC_EMBED; enc = false;
    }
    constexpr int BM = 64, BN = 64, BK = 64;
    int ctiles = N / BN;
    int rt = bx / ctiles, ct = bx % ctiles;

    __shared__ short Al[BM * BK];   // 8 KB, row-major [64][64]
    __shared__ short Bl[BN * BK];   // 8 KB, row-major [64][64]

    int t = threadIdx.x;
    int lane = t & 63;
    int w = t >> 6;
    int wr = w >> 1, wc = w & 1;
    int r0 = wr * 32;
    int c0 = wc * 32;

    int lrow = lane & 15;
    int kgrp = (lane >> 4) << 3;

    // staging: issue i covers shorts [i*2048 + t*8, +8); row = i*32 + t/8,
    // col = (t&7)*8 within the [*, 64] tile.
    int srow = t >> 3;
    int scol = (t & 7) * 8;

    int gA[2];
    #pragma unroll
    for (int i = 0; i < 2; ++i) {
        int r = rt * BM + i * 32 + srow;
        gA[i] = (r < M) ? r : M - 1;
    }
    const short* ap[2];
    #pragma unroll
    for (int i = 0; i < 2; ++i) ap[i] = A + (size_t)gA[i] * K + scol;
    const short* bp[2];
    #pragma unroll
    for (int i = 0; i < 2; ++i)
        bp[i] = Bt + (size_t)(ct * BN + i * 32 + srow) * K + scol;
    short* la[2];
    #pragma unroll
    for (int i = 0; i < 2; ++i) la[i] = &Al[i * 2048 + t * 8];
    short* lb[2];
    #pragma unroll
    for (int i = 0; i < 2; ++i) lb[i] = &Bl[i * 2048 + t * 8];

    f32x4 acc[2][2];
    #pragma unroll
    for (int mi = 0; mi < 2; ++mi)
        #pragma unroll
        for (int ni = 0; ni < 2; ++ni) acc[mi][ni] = f32x4{0.f, 0.f, 0.f, 0.f};

    for (int k0 = 0; k0 < K; k0 += BK) {
        #pragma unroll
        for (int i = 0; i < 2; ++i) gload_lds16(ap[i] + k0, la[i]);
        #pragma unroll
        for (int i = 0; i < 2; ++i) gload_lds16(bp[i] + k0, lb[i]);
        __syncthreads();
        #pragma unroll
        for (int ks = 0; ks < 2; ++ks) {
            short8 af[2], bf[2];
            #pragma unroll
            for (int mi = 0; mi < 2; ++mi)
                af[mi] = *reinterpret_cast<const short8*>(
                    &Al[(r0 + mi * 16 + lrow) * BK + ks * 32 + kgrp]);
            #pragma unroll
            for (int ni = 0; ni < 2; ++ni)
                bf[ni] = *reinterpret_cast<const short8*>(
                    &Bl[(c0 + ni * 16 + lrow) * BK + ks * 32 + kgrp]);
            #pragma unroll
            for (int mi = 0; mi < 2; ++mi)
                #pragma unroll
                for (int ni = 0; ni < 2; ++ni)
                    acc[mi][ni] = __builtin_amdgcn_mfma_f32_16x16x32_bf16(af[mi], bf[ni],
                                                                          acc[mi][ni],
                                                                          0, 0, 0);
        }
        __syncthreads();
    }

    int rbase = (lane >> 4) << 2;
    float mrow[2][4];
    bool fast = enc && (*notones == 0);
    #pragma unroll
    for (int mi = 0; mi < 2; ++mi)
        #pragma unroll
        for (int j = 0; j < 4; ++j) {
            float mv = 0.f;
            int row = rt * BM + r0 + mi * 16 + rbase + j;
            if (fast && row < M) {
                int s = inv[row];
                mv = segsum[s] / (float)max(segcnt[s], 1);
            }
            mrow[mi][j] = mv;
        }
    #pragma unroll
    for (int ni = 0; ni < 2; ++ni) {
        int col = ct * BN + c0 + ni * 16 + lrow;
        float bb = b2[col];
        #pragma unroll
        for (int mi = 0; mi < 2; ++mi) {
            #pragma unroll
            for (int j = 0; j < 4; ++j) {
                int row = rt * BM + r0 + mi * 16 + rbase + j;
                if (row < M) {
                    size_t o = (size_t)row * N + col;
                    out[o] = acc[mi][ni][j] + bb + mrow[mi][j];
                }
            }
        }
    }
}

// ---------------- host ----------------

extern "C" void kernel_launch(void* const* d_in, const int* in_sizes, int n_in,
                              void* d_out, int out_size, void* d_ws, size_t ws_size,
                              hipStream_t stream) {
    const float* sel_features = (const float*)d_in[0];
    const int*   q            = (const int*)d_in[1];
    const int*   seg          = (const int*)d_in[2];
    const int*   pad_idx      = (const int*)d_in[3];
    const float* coords       = (const float*)d_in[4];
    const float* sel_coors    = (const float*)d_in[5];
    const float* W            = (const float*)d_in[7];
    const float* w1e          = (const float*)d_in[8];
    const float* b1e          = (const float*)d_in[9];
    const float* w2e          = (const float*)d_in[10];
    const float* b2e          = (const float*)d_in[11];
    const float* w1d          = (const float*)d_in[12];
    const float* b1d          = (const float*)d_in[13];
    const float* w2d          = (const float*)d_in[14];
    const float* b2d          = (const float*)d_in[15];

    int npts    = in_sizes[1];
    int num_seg = in_sizes[3];
    int psize3  = in_sizes[7] / (IN_CHANS * EMBED);

    float* out  = (float*)d_out;
    float* out0 = out;                                       // [num_seg, 768]
    float* out1 = out0 + (size_t)num_seg * EMBED;            // sel_features copy
    float* out2 = out1 + (size_t)npts * IN_CHANS;            // sel_coors copy
    float* out3 = out2 + (size_t)npts * 3;                   // [num_seg, 512]

    // ws layout: hE | hD | w2tE | w2tD | segcnt | segsum | notones | inv
    char* wsb = (char*)d_ws;
    __hip_bfloat16* hE   = (__hip_bfloat16*)wsb;
    __hip_bfloat16* hD   = hE + (size_t)num_seg * EMBED;
    __hip_bfloat16* w2tE = hD + (size_t)num_seg * DEC_EMBED;
    __hip_bfloat16* w2tD = w2tE + (size_t)EMBED * EMBED;
    int*   segcnt  = (int*)(w2tD + (size_t)DEC_EMBED * DEC_EMBED);
    float* segsum  = (float*)(segcnt + num_seg);
    int*   notones = (int*)(segsum + num_seg);
    int*   inv     = notones + 1;            // [num_seg], fully written by scatter

    hipMemsetAsync(segcnt, 0, sizeof(int) * (size_t)(2 * num_seg + 1), stream);

    int hcBlocks = 1024, ckBlocks = 1024;
    int ntE = (EMBED / 32) * (EMBED / 32);
    int ntD = (DEC_EMBED / 32) * (DEC_EMBED / 32);
    hc_kernel<<<hcBlocks + ckBlocks + ntE + ntD, NTHREADS, 0, stream>>>(
        coords, w1e, b1e, w1d, b1d, seg, pad_idx, sel_features, sel_coors,
        w2e, w2d, W, hE, hD, w2tE, w2tD, segcnt, segsum, inv, notones, out1, out2,
        hcBlocks, ckBlocks, num_seg, npts, psize3);

    int rtiles = (num_seg + 63) / 64;
    int nblkE = rtiles * (EMBED / 64);
    int nblkD = rtiles * (DEC_EMBED / 64);
    gemm_lds_kernel<<<nblkE + nblkD, NTHREADS, 0, stream>>>(hE, w2tE, b2e, hD, w2tD, b2d,
                                                            notones, segsum, segcnt, inv,
                                                            out0, out3, num_seg, nblkE);

    fallback_project_kernel<<<256, NTHREADS, 0, stream>>>(notones, sel_features, q, seg,
                                                          segcnt, pad_idx, W, out0, npts);
}

// Round 21
// 68.844 us; speedup vs baseline: 2.8176x; 1.0452x over previous
//
#include <hip/hip_runtime.h>
#include <hip/hip_bf16.h>
#include <cmath>

#define NTHREADS 256

constexpr int IN_CHANS = 6;
constexpr int EMBED = 768;
constexpr int DEC_EMBED = 512;

typedef __attribute__((ext_vector_type(8))) short short8;
typedef __attribute__((ext_vector_type(4))) float f32x4;

__device__ __forceinline__ void gload_lds16(const short* g, short* l) {
    __builtin_amdgcn_global_load_lds((const __attribute__((address_space(1))) void*)g,
                                     (__attribute__((address_space(3))) void*)l, 16, 0, 0);
}

__device__ __forceinline__ float gelu_f(float x) {
    return 0.5f * x * (1.0f + erff(x * 0.70710678118654752f));
}

// ---- fused hc: 2 block roles ----
// [0, hcBlocks):  gelu h, segcnt+segsum, inv scatter, out1/out2 copies
// [hcBlocks, ..): w2 transpose tiles

__global__ void hc_kernel(const float* __restrict__ coords,
                          const float* __restrict__ w1e, const float* __restrict__ b1e,
                          const float* __restrict__ w1d, const float* __restrict__ b1d,
                          const int* __restrict__ seg, const int* __restrict__ pad_idx,
                          const float* __restrict__ sel, const float* __restrict__ selc,
                          const float* __restrict__ w2e, const float* __restrict__ w2d,
                          __hip_bfloat16* __restrict__ hE, __hip_bfloat16* __restrict__ hD,
                          __hip_bfloat16* __restrict__ w2tE, __hip_bfloat16* __restrict__ w2tD,
                          int* __restrict__ segcnt, float* __restrict__ segsum,
                          int* __restrict__ inv,
                          float* __restrict__ out1, float* __restrict__ out2,
                          int hcBlocks, int num_seg, int npts) {
    __shared__ float tile[32][33];
    int bid = blockIdx.x;
    if (bid >= hcBlocks) {
        // ---- transpose role ----
        int b = bid - hcBlocks;
        const float* src; __hip_bfloat16* dst; int n;
        const int ntE = (EMBED / 32) * (EMBED / 32);
        if (b < ntE) { src = w2e; dst = w2tE; n = EMBED; }
        else         { b -= ntE; src = w2d; dst = w2tD; n = DEC_EMBED; }
        int tpr = n / 32;
        int tr = b / tpr, tc = b % tpr;
        int tx = threadIdx.x & 31, ty = threadIdx.x >> 5;
        #pragma unroll
        for (int i = 0; i < 4; ++i)
            tile[ty + 8 * i][tx] = src[(size_t)(tr * 32 + ty + 8 * i) * n + tc * 32 + tx];
        __syncthreads();
        #pragma unroll
        for (int i = 0; i < 4; ++i)
            dst[(size_t)(tc * 32 + ty + 8 * i) * n + tr * 32 + tx] =
                __float2bfloat16(tile[tx][ty + 8 * i]);
        return;
    }
    // ---- main role ----
    const unsigned nE8 = (unsigned)num_seg * (EMBED / 8);
    const unsigned nD8 = (unsigned)num_seg * (DEC_EMBED / 8);
    const unsigned t0 = nE8;
    const unsigned t1 = t0 + nD8;
    const unsigned t2 = t1 + (unsigned)npts;
    const unsigned t2b = t2 + (unsigned)num_seg;
    const unsigned n14 = (unsigned)npts * IN_CHANS / 4;
    const unsigned t3 = t2b + n14;
    const unsigned n24 = (unsigned)npts * 3 / 4;
    const unsigned t4 = t3 + n24;
    const unsigned stride = (unsigned)hcBlocks * blockDim.x;
    for (unsigned idx = bid * blockDim.x + threadIdx.x; idx < t4; idx += stride) {
        if (idx < t0) {
            unsigned r = idx / (EMBED / 8), d = (idx % (EMBED / 8)) * 8;
            float c0 = coords[r * 3 + 0], c1 = coords[r * 3 + 1], c2 = coords[r * 3 + 2];
            float4 wa0 = *reinterpret_cast<const float4*>(w1e + 0 * EMBED + d);
            float4 wa1 = *reinterpret_cast<const float4*>(w1e + 0 * EMBED + d + 4);
            float4 wb0 = *reinterpret_cast<const float4*>(w1e + 1 * EMBED + d);
            float4 wb1 = *reinterpret_cast<const float4*>(w1e + 1 * EMBED + d + 4);
            float4 wc0 = *reinterpret_cast<const float4*>(w1e + 2 * EMBED + d);
            float4 wc1 = *reinterpret_cast<const float4*>(w1e + 2 * EMBED + d + 4);
            float4 bb0 = *reinterpret_cast<const float4*>(b1e + d);
            float4 bb1 = *reinterpret_cast<const float4*>(b1e + d + 4);
            union { short8 v; __hip_bfloat16 h[8]; } u;
            #pragma unroll
            for (int i = 0; i < 4; ++i)
                u.h[i] = __float2bfloat16(gelu_f(c0 * (&wa0.x)[i] + c1 * (&wb0.x)[i]
                                               + c2 * (&wc0.x)[i] + (&bb0.x)[i]));
            #pragma unroll
            for (int i = 0; i < 4; ++i)
                u.h[4 + i] = __float2bfloat16(gelu_f(c0 * (&wa1.x)[i] + c1 * (&wb1.x)[i]
                                                   + c2 * (&wc1.x)[i] + (&bb1.x)[i]));
            *reinterpret_cast<short8*>(&hE[(size_t)r * EMBED + d]) = u.v;
        } else if (idx < t1) {
            unsigned j = idx - t0;
            unsigned r = j / (DEC_EMBED / 8), d = (j % (DEC_EMBED / 8)) * 8;
            float c0 = coords[r * 3 + 0], c1 = coords[r * 3 + 1], c2 = coords[r * 3 + 2];
            float4 wa0 = *reinterpret_cast<const float4*>(w1d + 0 * DEC_EMBED + d);
            float4 wa1 = *reinterpret_cast<const float4*>(w1d + 0 * DEC_EMBED + d + 4);
            float4 wb0 = *reinterpret_cast<const float4*>(w1d + 1 * DEC_EMBED + d);
            float4 wb1 = *reinterpret_cast<const float4*>(w1d + 1 * DEC_EMBED + d + 4);
            float4 wc0 = *reinterpret_cast<const float4*>(w1d + 2 * DEC_EMBED + d);
            float4 wc1 = *reinterpret_cast<const float4*>(w1d + 2 * DEC_EMBED + d + 4);
            float4 bb0 = *reinterpret_cast<const float4*>(b1d + d);
            float4 bb1 = *reinterpret_cast<const float4*>(b1d + d + 4);
            union { short8 v; __hip_bfloat16 h[8]; } u;
            #pragma unroll
            for (int i = 0; i < 4; ++i)
                u.h[i] = __float2bfloat16(gelu_f(c0 * (&wa0.x)[i] + c1 * (&wb0.x)[i]
                                               + c2 * (&wc0.x)[i] + (&bb0.x)[i]));
            #pragma unroll
            for (int i = 0; i < 4; ++i)
                u.h[4 + i] = __float2bfloat16(gelu_f(c0 * (&wa1.x)[i] + c1 * (&wb1.x)[i]
                                                   + c2 * (&wc1.x)[i] + (&bb1.x)[i]));
            *reinterpret_cast<short8*>(&hD[(size_t)r * DEC_EMBED + d]) = u.v;
        } else if (idx < t2) {
            int i = (int)(idx - t1);
            int s = seg[i];
            atomicAdd(&segcnt[s], 1);
            const float2* s2 = reinterpret_cast<const float2*>(sel + (size_t)i * IN_CHANS);
            float2 a = s2[0], b = s2[1], c = s2[2];
            unsafeAtomicAdd(&segsum[s], a.x + a.y + b.x + b.y + c.x + c.y);
        } else if (idx < t2b) {
            int s = (int)(idx - t2);
            inv[pad_idx[s]] = s;
        } else if (idx < t3) {
            unsigned j = idx - t2b;
            reinterpret_cast<float4*>(out1)[j] =
                reinterpret_cast<const float4*>(sel)[j];
        } else {
            unsigned j = idx - t3;
            reinterpret_cast<float4*>(out2)[j] =
                reinterpret_cast<const float4*>(selc)[j];
        }
    }
}

// ---- fallback fix (W != 1, never expected): out0 += projection - mean ----
// All updates are commuting atomic adds; safe in one pass.

__global__ void fallback_fix_kernel(const int* __restrict__ notones,
                                    const float* __restrict__ sel,
                                    const int* __restrict__ q,
                                    const int* __restrict__ seg,
                                    const int* __restrict__ segcnt,
                                    const float* __restrict__ segsum,
                                    const int* __restrict__ pad_idx,
                                    const float* __restrict__ W,
                                    float* __restrict__ out0, int npts, int num_seg) {
    if (*notones == 0) return;
    long totalP = (long)npts * (EMBED / 4);
    long totalS = (long)num_seg * (EMBED / 4);
    long total = totalP + totalS;
    for (long idx = blockIdx.x * (long)blockDim.x + threadIdx.x; idx < total;
         idx += (long)gridDim.x * blockDim.x) {
        if (idx < totalP) {
            int n = (int)(idx / (EMBED / 4));
            int d4 = (int)(idx % (EMBED / 4)) * 4;
            int s = seg[n];
            float invc = 1.0f / (float)max(segcnt[s], 1);
            const float* Wr = W + (size_t)q[n] * IN_CHANS * EMBED + d4;
            float acc[4] = {0.f, 0.f, 0.f, 0.f};
            #pragma unroll
            for (int c = 0; c < IN_CHANS; ++c) {
                float sv = sel[(size_t)n * IN_CHANS + c];
                float4 wv = *reinterpret_cast<const float4*>(Wr + c * EMBED);
                acc[0] += sv * wv.x; acc[1] += sv * wv.y;
                acc[2] += sv * wv.z; acc[3] += sv * wv.w;
            }
            size_t j = (size_t)pad_idx[s];
            #pragma unroll
            for (int i = 0; i < 4; ++i)
                unsafeAtomicAdd(&out0[j * EMBED + d4 + i], acc[i] * invc);
        } else {
            long j2 = idx - totalP;
            int s = (int)(j2 / (EMBED / 4));
            int d4 = (int)(j2 % (EMBED / 4)) * 4;
            float mean = segsum[s] / (float)max(segcnt[s], 1);
            size_t j = (size_t)pad_idx[s];
            #pragma unroll
            for (int i = 0; i < 4; ++i)
                unsafeAtomicAdd(&out0[j * EMBED + d4 + i], -mean);
        }
    }
}

// ---- bf16 MFMA GEMM via LDS (BM=64 BN=64 BK=64) + embedded W-check role ----
// enc: out0 = h@w2 + b2 + mean[inv[row]] (mean always applied; fallback corrects)
// dec: out3 = h@w2 + b2.
// blocks [0, nblkTot): gemm tiles (XCD-swizzled); [nblkTot, +ck): W==1 check.

__global__ __launch_bounds__(256, 6)
void gemm_lds_kernel(const __hip_bfloat16* __restrict__ hE,
                     const __hip_bfloat16* __restrict__ w2tE,
                     const float* __restrict__ b2e,
                     const __hip_bfloat16* __restrict__ hD,
                     const __hip_bfloat16* __restrict__ w2tD,
                     const float* __restrict__ b2d,
                     const float* __restrict__ Wproj,
                     const float* __restrict__ segsum,
                     const int* __restrict__ segcnt,
                     const int* __restrict__ inv,
                     int* __restrict__ notones,
                     float* __restrict__ out0, float* __restrict__ out3,
                     int M, int nblkE, int nblkTot, int ckBlocks, int psize3) {
    int bid = blockIdx.x;
    if (bid >= nblkTot) {
        // ---- W-check role (overlaps with gemm compute) ----
        int b = bid - nblkTot;
        const unsigned total4 = (unsigned)psize3 * (IN_CHANS * EMBED / 4);
        const unsigned stride4 = (unsigned)ckBlocks * blockDim.x * 4u;
        const float4* p = reinterpret_cast<const float4*>(Wproj);
        bool bad = false;
        for (unsigned i = ((unsigned)b * blockDim.x + threadIdx.x) * 4u; i < total4;
             i += stride4) {
            float4 v0 = p[i], v1 = p[i + 1], v2 = p[i + 2], v3 = p[i + 3];
            bad |= v0.x != 1.f || v0.y != 1.f || v0.z != 1.f || v0.w != 1.f;
            bad |= v1.x != 1.f || v1.y != 1.f || v1.z != 1.f || v1.w != 1.f;
            bad |= v2.x != 1.f || v2.y != 1.f || v2.z != 1.f || v2.w != 1.f;
            bad |= v3.x != 1.f || v3.y != 1.f || v3.z != 1.f || v3.w != 1.f;
        }
        if (bad) atomicOr(notones, 1);
        return;
    }
    int q8 = nblkTot >> 3, r8 = nblkTot & 7;
    int xcd = bid & 7, idx = bid >> 3;
    int bx = (xcd < r8 ? xcd * (q8 + 1) : r8 * (q8 + 1) + (xcd - r8) * q8) + idx;

    const short* A;
    const short* Bt;
    const float* b2;
    float* out;
    int N, K;
    bool enc;
    if (bx < nblkE) {
        A = (const short*)hE; Bt = (const short*)w2tE; b2 = b2e; out = out0;
        N = EMBED; K = EMBED; enc = true;
    } else {
        bx -= nblkE;
        A = (const short*)hD; Bt = (const short*)w2tD; b2 = b2d; out = out3;
        N = DEC_EMBED; K = DEC_EMBED; enc = false;
    }
    constexpr int BM = 64, BN = 64, BK = 64;
    int ctiles = N / BN;
    int rt = bx / ctiles, ct = bx % ctiles;

    __shared__ short Al[BM * BK];
    __shared__ short Bl[BN * BK];

    int t = threadIdx.x;
    int lane = t & 63;
    int w = t >> 6;
    int wr = w >> 1, wc = w & 1;
    int r0 = wr * 32;
    int c0 = wc * 32;

    int lrow = lane & 15;
    int kgrp = (lane >> 4) << 3;

    int srow = t >> 3;
    int scol = (t & 7) * 8;

    int gA[2];
    #pragma unroll
    for (int i = 0; i < 2; ++i) {
        int r = rt * BM + i * 32 + srow;
        gA[i] = (r < M) ? r : M - 1;
    }
    const short* ap[2];
    #pragma unroll
    for (int i = 0; i < 2; ++i) ap[i] = A + (size_t)gA[i] * K + scol;
    const short* bp[2];
    #pragma unroll
    for (int i = 0; i < 2; ++i)
        bp[i] = Bt + (size_t)(ct * BN + i * 32 + srow) * K + scol;
    short* la[2];
    #pragma unroll
    for (int i = 0; i < 2; ++i) la[i] = &Al[i * 2048 + t * 8];
    short* lb[2];
    #pragma unroll
    for (int i = 0; i < 2; ++i) lb[i] = &Bl[i * 2048 + t * 8];

    f32x4 acc[2][2];
    #pragma unroll
    for (int mi = 0; mi < 2; ++mi)
        #pragma unroll
        for (int ni = 0; ni < 2; ++ni) acc[mi][ni] = f32x4{0.f, 0.f, 0.f, 0.f};

    for (int k0 = 0; k0 < K; k0 += BK) {
        #pragma unroll
        for (int i = 0; i < 2; ++i) gload_lds16(ap[i] + k0, la[i]);
        #pragma unroll
        for (int i = 0; i < 2; ++i) gload_lds16(bp[i] + k0, lb[i]);
        __syncthreads();
        #pragma unroll
        for (int ks = 0; ks < 2; ++ks) {
            short8 af[2], bf[2];
            #pragma unroll
            for (int mi = 0; mi < 2; ++mi)
                af[mi] = *reinterpret_cast<const short8*>(
                    &Al[(r0 + mi * 16 + lrow) * BK + ks * 32 + kgrp]);
            #pragma unroll
            for (int ni = 0; ni < 2; ++ni)
                bf[ni] = *reinterpret_cast<const short8*>(
                    &Bl[(c0 + ni * 16 + lrow) * BK + ks * 32 + kgrp]);
            #pragma unroll
            for (int mi = 0; mi < 2; ++mi)
                #pragma unroll
                for (int ni = 0; ni < 2; ++ni)
                    acc[mi][ni] = __builtin_amdgcn_mfma_f32_16x16x32_bf16(af[mi], bf[ni],
                                                                          acc[mi][ni],
                                                                          0, 0, 0);
        }
        __syncthreads();
    }

    int rbase = (lane >> 4) << 2;
    float mrow[2][4];
    #pragma unroll
    for (int mi = 0; mi < 2; ++mi)
        #pragma unroll
        for (int j = 0; j < 4; ++j) {
            float mv = 0.f;
            int row = rt * BM + r0 + mi * 16 + rbase + j;
            if (enc && row < M) {
                int s = inv[row];
                mv = segsum[s] / (float)max(segcnt[s], 1);
            }
            mrow[mi][j] = mv;
        }
    #pragma unroll
    for (int ni = 0; ni < 2; ++ni) {
        int col = ct * BN + c0 + ni * 16 + lrow;
        float bb = b2[col];
        #pragma unroll
        for (int mi = 0; mi < 2; ++mi) {
            #pragma unroll
            for (int j = 0; j < 4; ++j) {
                int row = rt * BM + r0 + mi * 16 + rbase + j;
                if (row < M) {
                    size_t o = (size_t)row * N + col;
                    out[o] = acc[mi][ni][j] + bb + mrow[mi][j];
                }
            }
        }
    }
}

// ---------------- host ----------------

extern "C" void kernel_launch(void* const* d_in, const int* in_sizes, int n_in,
                              void* d_out, int out_size, void* d_ws, size_t ws_size,
                              hipStream_t stream) {
    const float* sel_features = (const float*)d_in[0];
    const int*   q            = (const int*)d_in[1];
    const int*   seg          = (const int*)d_in[2];
    const int*   pad_idx      = (const int*)d_in[3];
    const float* coords       = (const float*)d_in[4];
    const float* sel_coors    = (const float*)d_in[5];
    const float* W            = (const float*)d_in[7];
    const float* w1e          = (const float*)d_in[8];
    const float* b1e          = (const float*)d_in[9];
    const float* w2e          = (const float*)d_in[10];
    const float* b2e          = (const float*)d_in[11];
    const float* w1d          = (const float*)d_in[12];
    const float* b1d          = (const float*)d_in[13];
    const float* w2d          = (const float*)d_in[14];
    const float* b2d          = (const float*)d_in[15];

    int npts    = in_sizes[1];
    int num_seg = in_sizes[3];
    int psize3  = in_sizes[7] / (IN_CHANS * EMBED);

    float* out  = (float*)d_out;
    float* out0 = out;                                       // [num_seg, 768]
    float* out1 = out0 + (size_t)num_seg * EMBED;            // sel_features copy
    float* out2 = out1 + (size_t)npts * IN_CHANS;            // sel_coors copy
    float* out3 = out2 + (size_t)npts * 3;                   // [num_seg, 512]

    // ws layout: hE | hD | w2tE | w2tD | segcnt | segsum | notones | inv
    char* wsb = (char*)d_ws;
    __hip_bfloat16* hE   = (__hip_bfloat16*)wsb;
    __hip_bfloat16* hD   = hE + (size_t)num_seg * EMBED;
    __hip_bfloat16* w2tE = hD + (size_t)num_seg * DEC_EMBED;
    __hip_bfloat16* w2tD = w2tE + (size_t)EMBED * EMBED;
    int*   segcnt  = (int*)(w2tD + (size_t)DEC_EMBED * DEC_EMBED);
    float* segsum  = (float*)(segcnt + num_seg);
    int*   notones = (int*)(segsum + num_seg);
    int*   inv     = notones + 1;            // [num_seg]

    hipMemsetAsync(segcnt, 0, sizeof(int) * (size_t)(2 * num_seg + 1), stream);

    int hcBlocks = 1024;
    int ntE = (EMBED / 32) * (EMBED / 32);
    int ntD = (DEC_EMBED / 32) * (DEC_EMBED / 32);
    hc_kernel<<<hcBlocks + ntE + ntD, NTHREADS, 0, stream>>>(
        coords, w1e, b1e, w1d, b1d, seg, pad_idx, sel_features, sel_coors,
        w2e, w2d, hE, hD, w2tE, w2tD, segcnt, segsum, inv, out1, out2,
        hcBlocks, num_seg, npts);

    int rtiles = (num_seg + 63) / 64;
    int nblkE = rtiles * (EMBED / 64);
    int nblkD = rtiles * (DEC_EMBED / 64);
    int nblkTot = nblkE + nblkD;
    int ckBlocks = 1024;
    gemm_lds_kernel<<<nblkTot + ckBlocks, NTHREADS, 0, stream>>>(
        hE, w2tE, b2e, hD, w2tD, b2d, W, segsum, segcnt, inv, notones,
        out0, out3, num_seg, nblkE, nblkTot, ckBlocks, psize3);

    fallback_fix_kernel<<<256, NTHREADS, 0, stream>>>(notones, sel_features, q, seg,
                                                      segcnt, segsum, pad_idx, W,
                                                      out0, npts, num_seg);
}